// Round 10
// baseline (160.732 us; speedup 1.0000x reference)
//
#include <hip/hip_runtime.h>

#define VB 0.22360679774997896f  // 20^-0.5

typedef __attribute__((ext_vector_type(8))) _Float16 half8;
typedef __attribute__((ext_vector_type(4))) float f32x4;

// workspace float offsets
#define Z1_OFF   0
#define Z2_OFF   655360
#define Z3_OFF   819200
#define GS1_OFF  860160
#define GQ1_OFF  860416
#define GS2_OFF  860672
#define GQ2_OFF  860736
#define GS3_OFF  860800
#define GQ3_OFF  860816
#define LV1_OFF  860832    // 256*400
#define LV2_OFF  963232    // 64*400
#define LV3_OFF  988832    // 16*400
#define XT_OFF   995232    // 1024*6144 = 6291456 floats
#define WH1_OFF  7286688   // 39321600 halfs = 19660800 floats
#define WH2_OFF  26947488  // 6553600 halfs  = 3276800 floats
#define WH3_OFF  30224288  // 1638400 halfs  = 819200 floats ; end 31043488 fl

#define WAVEBAR() __builtin_amdgcn_wave_barrier()

// ---------------------------------------------------------------------------
// Merged prep, max-MLP version. Grid 25585 x 256, launch_bounds(256,8).
//   [0,2048)       : x transpose, 16x192 tiles (LDS 12.4 KB -> no occ cap)
//   [2048,21248)   : cores1 -> fp16 B-frag, FLAT: 1 half8 per thread,
//                    single load-round (8 stride-20 dwords), no LDS
//   [21248,25248)  : cores2/3 -> fp16 B-frag, flat (f>=40 zero-padded)
//   [25248,25584)  : label pre-contraction (float4 reads)
//   25584          : zero BN atomic-sum region
// ---------------------------------------------------------------------------
__global__ __launch_bounds__(256, 8)
void prep_kernel(const float* __restrict__ x,
                 const float* __restrict__ cores1,
                 const float* __restrict__ c2, const float* __restrict__ c3,
                 const float* __restrict__ l1, const float* __restrict__ l2,
                 const float* __restrict__ l3,
                 float* __restrict__ xT,
                 _Float16* __restrict__ Wh1, _Float16* __restrict__ Wh2,
                 _Float16* __restrict__ Wh3,
                 float* __restrict__ v1, float* __restrict__ v2,
                 float* __restrict__ v3,
                 float* __restrict__ gzero)
{
    __shared__ __align__(16) float tS[16 * 193];   // 12352 B, xt branch only
    const int tid = threadIdx.x;
    const int b   = blockIdx.x;

    if (b < 2048) {
        // ---- x transpose: 16 pix x 192 bc tile ----
        const int pix0 = (b & 63) * 16;
        const int bc0  = (b >> 6) * 192;
        #pragma unroll
        for (int k = 0; k < 3; ++k) {
            int i = tid + k * 256;                 // < 768
            int r = i >> 2, q = i & 3;
            float4 v = *(const float4*)(x + (size_t)(bc0 + r) * 1024 + pix0 + q * 4);
            tS[(q * 4 + 0) * 193 + r] = v.x;
            tS[(q * 4 + 1) * 193 + r] = v.y;
            tS[(q * 4 + 2) * 193 + r] = v.z;
            tS[(q * 4 + 3) * 193 + r] = v.w;
        }
        __syncthreads();
        #pragma unroll
        for (int k = 0; k < 3; ++k) {
            int o = tid + k * 256;                 // < 768
            int pp = o / 48, c4 = o - pp * 48;
            float4 v;
            v.x = tS[pp * 193 + c4 * 4 + 0];
            v.y = tS[pp * 193 + c4 * 4 + 1];
            v.z = tS[pp * 193 + c4 * 4 + 2];
            v.w = tS[pp * 193 + c4 * 4 + 3];
            *(float4*)(xT + (size_t)(pix0 + pp) * 6144 + bc0 + c4 * 4) = v;
        }
    } else if (b < 21248) {
        // ---- wconv1: one output half8 per thread, single latency round ----
        int gidx = (b - 2048) * 256 + tid;         // < 4915200
        int slab = gidx / 960;
        int o    = gidx - slab * 960;
        int q  = o >> 6, l = o & 63;
        int ks = q / 5, nt = q - ks * 5;
        int c  = nt * 16 + (l & 15);
        int ul = c / 20;
        int v  = c - ul * 20;
        int f0 = ks * 32 + ((l >> 4) << 3);
        const float* sp = cores1 + (size_t)slab * 7680 + ul * 1920 + f0 * 20 + v;
        half8 hv;
        #pragma unroll
        for (int j = 0; j < 8; ++j) hv[j] = (_Float16)sp[j * 20];
        *(half8*)(Wh1 + (size_t)gidx * 8) = hv;
    } else if (b < 25248) {
        // ---- wconv2/3: flat, f>=40 zero-padded ----
        int gidx = (b - 21248) * 256 + tid;        // < 1024000
        int bb = gidx / 640;
        int o  = gidx - bb * 640;
        const float* src;
        _Float16* dst;
        if (bb < 1280) { src = c2 + (size_t)bb * 3200;          dst = Wh2 + (size_t)bb * 5120; }
        else           { src = c3 + (size_t)(bb - 1280) * 3200; dst = Wh3 + (size_t)(bb - 1280) * 5120; }
        int q  = o >> 6, l = o & 63;
        int ks = q / 5, nt = q - ks * 5;
        int c  = nt * 16 + (l & 15);
        int ul = c / 20;
        int v  = c - ul * 20;
        int f0 = ks * 32 + ((l >> 4) << 3);
        half8 hv;
        if (f0 < 40) {
            const float* sp = src + ul * 800 + f0 * 20 + v;
            #pragma unroll
            for (int j = 0; j < 8; ++j) hv[j] = (_Float16)sp[j * 20];
        } else {
            #pragma unroll
            for (int j = 0; j < 8; ++j) hv[j] = (_Float16)0.f;
        }
        *(half8*)(dst + (size_t)o * 8) = hv;
    } else if (b < 25584) {
        // ---- label pre-contraction (float4 reads) ----
        const int bb = b - 25248;
        const float* lb;
        float* ov;
        if (bb < 256)      { lb = l1 + (size_t)bb * 8000;         ov = v1 + bb * 400; }
        else if (bb < 320) { lb = l2 + (size_t)(bb - 256) * 8000; ov = v2 + (bb - 256) * 400; }
        else               { lb = l3 + (size_t)(bb - 320) * 8000; ov = v3 + (bb - 320) * 400; }
        for (int i = tid; i < 400; i += 256) {
            const float4* s = (const float4*)(lb + i * 20);
            float acc = 0.f;
            #pragma unroll
            for (int t = 0; t < 5; ++t) {
                float4 w = s[t];
                acc += w.x + w.y + w.z + w.w;
            }
            ov[i] = acc * VB;
        }
    } else {
        // ---- zero BN sums ----
        for (int i = tid; i < 672; i += 256) gzero[i] = 0.f;
    }
}

// ---------------------------------------------------------------------------
// Fused stage 1 (verified R7/R8/R9): grid (256 p, 2 bh) x 256 thr, zero block
// barriers, wave-private 16 batch rows, B-frags global->reg double-buffered.
// ---------------------------------------------------------------------------
#define UCBODY1(ucv, CUR, NXT)                                                   \
    {                                                                            \
        if ((ucv) < 4) {                                                         \
            const _Float16* bptr = whp + (size_t)((ucv) + 1) * 7680;             \
            _Pragma("unroll")                                                    \
            for (int q = 0; q < 15; ++q)                                         \
                NXT[q] = *(const half8*)(bptr + (q * 64 + l) * 8);               \
        }                                                                        \
        f32x4 acc[5];                                                            \
        _Pragma("unroll")                                                        \
        for (int nt = 0; nt < 5; ++nt) acc[nt] = (f32x4){0.f, 0.f, 0.f, 0.f};    \
        _Pragma("unroll")                                                        \
        for (int ks = 0; ks < 3; ++ks) {                                         \
            _Pragma("unroll")                                                    \
            for (int nt = 0; nt < 5; ++nt)                                       \
                acc[nt] = __builtin_amdgcn_mfma_f32_16x16x32_f16(                \
                    af[ks], CUR[ks * 5 + nt], acc[nt], 0, 0, 0);                 \
        }                                                                        \
        _Pragma("unroll")                                                        \
        for (int nt = 0; nt < 5; ++nt) {                                         \
            _Pragma("unroll")                                                    \
            for (int r = 0; r < 4; ++r)                                          \
                Mw[(hi * 4 + r) * 84 + nt * 16 + row16] = acc[nt][r];            \
        }                                                                        \
        WAVEBAR();                                                               \
        _Pragma("unroll")                                                        \
        for (int ul = 0; ul < 4; ++ul) {                                         \
            float lvx = lw[bQ * 20 + (ucv) * 4 + ul];                            \
            _Pragma("unroll")                                                    \
            for (int j = 0; j < 5; ++j)                                          \
                lacc[j] += lvx * Mw[bQ * 84 + ul * 20 + mh * 5 + j];             \
        }                                                                        \
        WAVEBAR();                                                               \
    }

__global__ __launch_bounds__(256, 2)
void fused1_kernel(const float* __restrict__ xT, const _Float16* __restrict__ Wh,
                   const float* __restrict__ labv,
                   float* __restrict__ z1, float* __restrict__ gs, float* __restrict__ gq)
{
    __shared__ __align__(16) float xS[4 * 768];
    __shared__ __align__(16) float MchunkS[4 * 16 * 84];
    __shared__ __align__(16) float leftS[4 * 320];

    const int tid = threadIdx.x;
    const int p   = blockIdx.x;
    const int bh  = blockIdx.y;
    const int wv  = tid >> 6, l = tid & 63;
    float* xSw = xS + wv * 768;
    float* Mw  = MchunkS + wv * 1344;
    float* lw  = leftS + wv * 320;
    const int row16 = l & 15, hi = l >> 4;
    const int bQ = l >> 2,   mh = l & 3;
    const int hh  = (p >> 7) * 16 + ((p >> 2) & 15);
    const int ww0 = ((p >> 6) & 1) * 16 + (p & 3) * 4;

    #pragma unroll
    for (int j = 0; j < 5; ++j) lw[bQ * 20 + mh * 5 + j] = VB;
    WAVEBAR();

    float lacc[5] = {0.f, 0.f, 0.f, 0.f, 0.f};

    #pragma unroll 1
    for (int n = 0; n < 4; ++n) {
        const float* xsl = xT + (size_t)(hh * 32 + ww0 + n) * 6144 + bh * 3072 + wv * 768;
        #pragma unroll
        for (int k = 0; k < 3; ++k) {
            float4 v = *(const float4*)(xsl + (l + k * 64) * 4);
            *(float4*)&xSw[(l + k * 64) * 4] = v;
        }
        WAVEBAR();
        half8 af[3];
        #pragma unroll
        for (int ks = 0; ks < 3; ++ks) {
            int f0 = ks * 32 + hi * 8;
            int cc = (f0 < 48) ? f0 : f0 - 48;
            float4 a  = *(const float4*)&xSw[row16 * 48 + cc];
            float4 b2 = *(const float4*)&xSw[row16 * 48 + cc + 4];
            float vv[8] = {a.x, a.y, a.z, a.w, b2.x, b2.y, b2.z, b2.w};
            bool inv = (f0 >= 48);
            half8 hv;
            #pragma unroll
            for (int j = 0; j < 8; ++j) hv[j] = (_Float16)(inv ? (1.f - vv[j]) : vv[j]);
            af[ks] = hv;
        }
        WAVEBAR();

        const _Float16* whp = Wh + (size_t)((p * 4 + n) * 5) * 7680;
        half8 bA[15], bB[15];
        {
            #pragma unroll
            for (int q = 0; q < 15; ++q) bA[q] = *(const half8*)(whp + (q * 64 + l) * 8);
        }
        UCBODY1(0, bA, bB)
        UCBODY1(1, bB, bA)
        UCBODY1(2, bA, bB)
        UCBODY1(3, bB, bA)
        UCBODY1(4, bA, bB)

        #pragma unroll
        for (int j = 0; j < 5; ++j) { lw[bQ * 20 + mh * 5 + j] = lacc[j]; lacc[j] = 0.f; }
        WAVEBAR();
    }

    const float* lvp = labv + p * 400;
    #pragma unroll
    for (int k = 0; k < 7; ++k) { int i = l + k * 64; if (i < 400) Mw[i] = lvp[i]; }
    WAVEBAR();
    float yv[5] = {0.f, 0.f, 0.f, 0.f, 0.f};
    #pragma unroll
    for (int u = 0; u < 20; ++u) {
        float lu = lw[bQ * 20 + u];
        #pragma unroll
        for (int j = 0; j < 5; ++j) yv[j] += lu * Mw[u * 20 + mh * 5 + j];
    }
    float s = 0.f, s2 = 0.f;
    #pragma unroll
    for (int j = 0; j < 5; ++j) {
        z1[(size_t)(bh * 64 + wv * 16 + bQ) * 5120 + p * 20 + mh * 5 + j] = yv[j];
        s += yv[j]; s2 += yv[j] * yv[j];
    }
    #pragma unroll
    for (int off = 32; off > 0; off >>= 1) {
        s  += __shfl_down(s, off);
        s2 += __shfl_down(s2, off);
    }
    if (l == 0) { atomicAdd(&gs[p], s); atomicAdd(&gq[p], s2); }
}

// ---------------------------------------------------------------------------
// Fused stages 2 & 3 (verified R7/R8/R9)
// ---------------------------------------------------------------------------
#define UCBODYN(ucv, CUR, NXT)                                                   \
    {                                                                            \
        if ((ucv) < 4) {                                                         \
            const _Float16* bptr = whp + (size_t)((ucv) + 1) * 5120;             \
            _Pragma("unroll")                                                    \
            for (int q = 0; q < 10; ++q)                                         \
                NXT[q] = *(const half8*)(bptr + (q * 64 + l) * 8);               \
        }                                                                        \
        f32x4 acc[5];                                                            \
        _Pragma("unroll")                                                        \
        for (int nt = 0; nt < 5; ++nt) acc[nt] = (f32x4){0.f, 0.f, 0.f, 0.f};    \
        _Pragma("unroll")                                                        \
        for (int ks = 0; ks < 2; ++ks) {                                         \
            _Pragma("unroll")                                                    \
            for (int nt = 0; nt < 5; ++nt)                                       \
                acc[nt] = __builtin_amdgcn_mfma_f32_16x16x32_f16(                \
                    af[ks], CUR[ks * 5 + nt], acc[nt], 0, 0, 0);                 \
        }                                                                        \
        _Pragma("unroll")                                                        \
        for (int nt = 0; nt < 5; ++nt) {                                         \
            _Pragma("unroll")                                                    \
            for (int r = 0; r < 4; ++r)                                          \
                Mw[(hi * 4 + r) * 84 + nt * 16 + row16] = acc[nt][r];            \
        }                                                                        \
        WAVEBAR();                                                               \
        _Pragma("unroll")                                                        \
        for (int ul = 0; ul < 4; ++ul) {                                         \
            float lvx = lw[bQ * 20 + (ucv) * 4 + ul];                            \
            _Pragma("unroll")                                                    \
            for (int j = 0; j < 5; ++j)                                          \
                lacc[j] += lvx * Mw[bQ * 84 + ul * 20 + mh * 5 + j];             \
        }                                                                        \
        WAVEBAR();                                                               \
    }

template <int STAGE>
__global__ __launch_bounds__(256, 2)
void fusedN_kernel(const float* __restrict__ zin, const _Float16* __restrict__ Wh,
                   const float* __restrict__ labv,
                   const float* __restrict__ gsin, const float* __restrict__ gqin,
                   const float* __restrict__ gam,  const float* __restrict__ bet,
                   float* __restrict__ zout,
                   float* __restrict__ gsout, float* __restrict__ gqout)
{
    constexpr int ZIN  = (STAGE == 2) ? 5120 : 1280;
    constexpr int ZOUT = (STAGE == 2) ? 1280 : 320;
    constexpr int JUMP = (STAGE == 2) ? 256 : 64;

    __shared__ __align__(16) float zS[4 * 320];
    __shared__ float scS[4 * 20], shS[4 * 20];
    __shared__ __align__(16) float MchunkS[4 * 16 * 84];
    __shared__ __align__(16) float leftS[4 * 320];

    const int tid = threadIdx.x;
    const int p   = blockIdx.x;
    const int bh  = blockIdx.y;
    const int wv  = tid >> 6, l = tid & 63;
    float* zSw = zS + wv * 320;
    float* scw = scS + wv * 20;
    float* shw = shS + wv * 20;
    float* Mw  = MchunkS + wv * 1344;
    float* lw  = leftS + wv * 320;
    const int row16 = l & 15, hi = l >> 4;
    const int bQ = l >> 2,   mh = l & 3;
    const int bg = bh * 64;

    #pragma unroll
    for (int j = 0; j < 5; ++j) lw[bQ * 20 + mh * 5 + j] = VB;
    WAVEBAR();

    float lacc[5] = {0.f, 0.f, 0.f, 0.f, 0.f};

    #pragma unroll 1
    for (int n = 0; n < 4; ++n) {
        int hh, ww;
        if (STAGE == 2) { hh = (p >> 5) * 8 + ((p >> 1) & 7); ww = ((p >> 4) & 1) * 8 + (p & 1) * 4 + n; }
        else            { hh = (p >> 3) * 4 + (p & 3);        ww = ((p >> 2) & 1) * 4 + n; }
        const int oo = (STAGE == 2) ? (hh * 16 + ww) : (hh * 8 + ww);

        if (l < 20) {
            int ch = (l * JUMP + oo) / 20;
            float mean = gsin[ch] * (1.f / 2560.f);
            float var  = gqin[ch] * (1.f / 2560.f) - mean * mean;
            float rstd = rsqrtf(var + 1e-5f);
            float sc = gam[ch] * rstd;
            scw[l] = sc;
            shw[l] = bet[ch] - mean * sc;
        }
        WAVEBAR();
        #pragma unroll
        for (int q = 0; q < 5; ++q) {
            int d = hi * 5 + q;
            float zraw = zin[(size_t)(bg + wv * 16 + row16) * ZIN + d * JUMP + oo];
            zSw[row16 * 20 + d] = zraw * scw[d] + shw[d];
        }
        WAVEBAR();
        half8 af[2];
        #pragma unroll
        for (int ks = 0; ks < 2; ++ks) {
            int f0 = ks * 32 + hi * 8;
            half8 hv;
            #pragma unroll
            for (int j = 0; j < 8; ++j) {
                int f = f0 + j;
                float val;
                if (f < 20)      val = zSw[row16 * 20 + f];
                else if (f < 40) val = 1.f - zSw[row16 * 20 + f - 20];
                else             val = 0.f;
                hv[j] = (_Float16)val;
            }
            af[ks] = hv;
        }
        WAVEBAR();

        const _Float16* whp = Wh + (size_t)((p * 4 + n) * 5) * 5120;
        half8 bA[10], bB[10];
        {
            #pragma unroll
            for (int q = 0; q < 10; ++q) bA[q] = *(const half8*)(whp + (q * 64 + l) * 8);
        }
        UCBODYN(0, bA, bB)
        UCBODYN(1, bB, bA)
        UCBODYN(2, bA, bB)
        UCBODYN(3, bB, bA)
        UCBODYN(4, bA, bB)

        #pragma unroll
        for (int j = 0; j < 5; ++j) { lw[bQ * 20 + mh * 5 + j] = lacc[j]; lacc[j] = 0.f; }
        WAVEBAR();
    }

    const float* lvp = labv + p * 400;
    #pragma unroll
    for (int k = 0; k < 7; ++k) { int i = l + k * 64; if (i < 400) Mw[i] = lvp[i]; }
    WAVEBAR();
    float yv[5] = {0.f, 0.f, 0.f, 0.f, 0.f};
    #pragma unroll
    for (int u = 0; u < 20; ++u) {
        float lu = lw[bQ * 20 + u];
        #pragma unroll
        for (int j = 0; j < 5; ++j) yv[j] += lu * Mw[u * 20 + mh * 5 + j];
    }
    float s = 0.f, s2 = 0.f;
    #pragma unroll
    for (int j = 0; j < 5; ++j) {
        zout[(size_t)(bg + wv * 16 + bQ) * ZOUT + p * 20 + mh * 5 + j] = yv[j];
        s += yv[j]; s2 += yv[j] * yv[j];
    }
    #pragma unroll
    for (int off = 32; off > 0; off >>= 1) {
        s  += __shfl_down(s, off);
        s2 += __shfl_down(s2, off);
    }
    if (l == 0) { atomicAdd(&gsout[p], s); atomicAdd(&gqout[p], s2); }
}

// ---------------------------------------------------------------------------
// Final MPS (verified R8/R9): parallel M build, single-wave chain.
// ---------------------------------------------------------------------------
__global__ __launch_bounds__(256, 4)
void final_kernel(const float* __restrict__ z3,
                  const float* __restrict__ coresF,
                  const float* __restrict__ labelF,
                  const float* __restrict__ g3,
                  const float* __restrict__ b3,
                  const float* __restrict__ gsum3,
                  const float* __restrict__ gsq3,
                  float* __restrict__ out)
{
    __shared__ __align__(16) float fS[16 * 40];
    __shared__ __align__(16) float MS[16 * 400];
    __shared__ float lvS[200];
    __shared__ float scS[16], shS[16];
    __shared__ float leftS[20];

    const int b   = blockIdx.x;
    const int tid = threadIdx.x;

    if (tid < 16) {
        float mean = gsum3[tid] * (1.f / 2560.f);
        float var  = gsq3[tid] * (1.f / 2560.f) - mean * mean;
        float rstd = rsqrtf(var + 1e-5f);
        float sc   = g3[tid] * rstd;
        scS[tid] = sc;
        shS[tid] = b3[tid] - mean * sc;
    }
    __syncthreads();

    for (int i = tid; i < 640; i += 256) {
        int n = i / 40, f = i - n * 40;
        float raw = z3[(size_t)b * 320 + n * 20 + (f % 20)];
        float val = raw * scS[n] + shS[n];
        fS[i] = (f < 20) ? val : (1.f - val);
    }
    for (int i = tid; i < 200; i += 256) {
        int u = i / 10, o = i - u * 10;
        const float* lb = labelF + (size_t)(u * 10 + o) * 20;
        float s = 0.f;
        #pragma unroll
        for (int vv = 0; vv < 20; ++vv) s += lb[vv];
        lvS[i] = s * VB;
    }
    __syncthreads();

    for (int i = tid; i < 6400; i += 256) {
        int n = i / 400, uv = i - n * 400;
        int u = uv / 20, v = uv - u * 20;
        const float* wb = coresF + ((size_t)(n * 20 + u) * 40) * 20 + v;
        const float* fb = fS + n * 40;
        float acc = 0.f;
        #pragma unroll
        for (int f = 0; f < 40; ++f) acc += fb[f] * wb[f * 20];
        MS[i] = acc;
    }
    __syncthreads();

    if (tid < 64) {
        if (tid < 20) leftS[tid] = VB;
        WAVEBAR();
        #pragma unroll 1
        for (int n = 0; n < 16; ++n) {
            float tmp = 0.f;
            if (tid < 20) {
                #pragma unroll
                for (int u = 0; u < 20; ++u) tmp += leftS[u] * MS[n * 400 + u * 20 + tid];
            }
            WAVEBAR();
            if (tid < 20) leftS[tid] = tmp;
            WAVEBAR();
        }
        if (tid < 10) {
            float s = 0.f;
            #pragma unroll
            for (int u = 0; u < 20; ++u) s += leftS[u] * lvS[u * 10 + tid];
            out[b * 10 + tid] = s;
        }
    }
}

// ---------------------------------------------------------------------------
extern "C" void kernel_launch(void* const* d_in, const int* in_sizes, int n_in,
                              void* d_out, int out_size, void* d_ws, size_t ws_size,
                              hipStream_t stream)
{
    const float* x      = (const float*)d_in[0];
    const float* cores1 = (const float*)d_in[1];
    const float* label1 = (const float*)d_in[2];
    const float* g1     = (const float*)d_in[3];
    const float* b1     = (const float*)d_in[4];
    const float* cores2 = (const float*)d_in[5];
    const float* label2 = (const float*)d_in[6];
    const float* g2     = (const float*)d_in[7];
    const float* b2     = (const float*)d_in[8];
    const float* cores3 = (const float*)d_in[9];
    const float* label3 = (const float*)d_in[10];
    const float* g3     = (const float*)d_in[11];
    const float* b3     = (const float*)d_in[12];
    const float* coresF = (const float*)d_in[13];
    const float* labelF = (const float*)d_in[14];

    float* ws  = (float*)d_ws;
    float* z1  = ws + Z1_OFF;
    float* z2  = ws + Z2_OFF;
    float* z3  = ws + Z3_OFF;
    float* gs1 = ws + GS1_OFF; float* gq1 = ws + GQ1_OFF;
    float* gs2 = ws + GS2_OFF; float* gq2 = ws + GQ2_OFF;
    float* gs3 = ws + GS3_OFF; float* gq3 = ws + GQ3_OFF;
    float* lv1 = ws + LV1_OFF;
    float* lv2 = ws + LV2_OFF;
    float* lv3 = ws + LV3_OFF;
    float* xT  = ws + XT_OFF;
    _Float16* Wh1 = (_Float16*)(ws + WH1_OFF);
    _Float16* Wh2 = (_Float16*)(ws + WH2_OFF);
    _Float16* Wh3 = (_Float16*)(ws + WH3_OFF);

    prep_kernel<<<25585, 256, 0, stream>>>(x, cores1, cores2, cores3,
                                           label1, label2, label3,
                                           xT, Wh1, Wh2, Wh3,
                                           lv1, lv2, lv3, gs1);

    fused1_kernel<<<dim3(256, 2), 256, 0, stream>>>(xT, Wh1, lv1, z1, gs1, gq1);
    fusedN_kernel<2><<<dim3(64, 2), 256, 0, stream>>>(z1, Wh2, lv2, gs1, gq1, g1, b1,
                                                      z2, gs2, gq2);
    fusedN_kernel<3><<<dim3(16, 2), 256, 0, stream>>>(z2, Wh3, lv3, gs2, gq2, g2, b2,
                                                      z3, gs3, gq3);
    final_kernel<<<128, 256, 0, stream>>>(z3, coresF, labelF, g3, b3,
                                          gs3, gq3, (float*)d_out);
}

// Round 11
// 144.680 us; speedup vs baseline: 1.1109x; 1.1109x over previous
//
#include <hip/hip_runtime.h>

#define VB 0.22360679774997896f  // 20^-0.5

typedef __attribute__((ext_vector_type(8))) _Float16 half8;
typedef __attribute__((ext_vector_type(4))) float f32x4;

// workspace float offsets
#define Z1_OFF   0
#define Z2_OFF   655360
#define Z3_OFF   819200
#define GS1_OFF  860160
#define GQ1_OFF  860416
#define GS2_OFF  860672
#define GQ2_OFF  860736
#define GS3_OFF  860800
#define GQ3_OFF  860816
#define LV1_OFF  860832    // 256*400
#define LV2_OFF  963232    // 64*400
#define LV3_OFF  988832    // 16*400
#define XT_OFF   995232    // 1024*6144 = 6291456 floats
#define WH2_OFF  7286688   // 6553600 halfs = 3276800 floats
#define WH3_OFF  10563488  // 1638400 halfs = 819200 floats ; end 11382688 fl

#define WAVEBAR() __builtin_amdgcn_wave_barrier()

// ---------------------------------------------------------------------------
// Merged prep (wconv1 ELIMINATED). Grid 6385 x 256, launch_bounds(256,8).
//   [0,2048)     : x transpose, 16x192 tiles
//   [2048,6048)  : cores2/3 -> fp16 B-frag, flat 1 half8/thread
//   [6048,6384)  : label pre-contraction
//   6384         : zero BN atomic-sum region
// ---------------------------------------------------------------------------
__global__ __launch_bounds__(256, 8)
void prep_kernel(const float* __restrict__ x,
                 const float* __restrict__ c2, const float* __restrict__ c3,
                 const float* __restrict__ l1, const float* __restrict__ l2,
                 const float* __restrict__ l3,
                 float* __restrict__ xT,
                 _Float16* __restrict__ Wh2, _Float16* __restrict__ Wh3,
                 float* __restrict__ v1, float* __restrict__ v2,
                 float* __restrict__ v3,
                 float* __restrict__ gzero)
{
    __shared__ __align__(16) float tS[16 * 193];
    const int tid = threadIdx.x;
    const int b   = blockIdx.x;

    if (b < 2048) {
        const int pix0 = (b & 63) * 16;
        const int bc0  = (b >> 6) * 192;
        #pragma unroll
        for (int k = 0; k < 3; ++k) {
            int i = tid + k * 256;
            int r = i >> 2, q = i & 3;
            float4 v = *(const float4*)(x + (size_t)(bc0 + r) * 1024 + pix0 + q * 4);
            tS[(q * 4 + 0) * 193 + r] = v.x;
            tS[(q * 4 + 1) * 193 + r] = v.y;
            tS[(q * 4 + 2) * 193 + r] = v.z;
            tS[(q * 4 + 3) * 193 + r] = v.w;
        }
        __syncthreads();
        #pragma unroll
        for (int k = 0; k < 3; ++k) {
            int o = tid + k * 256;
            int pp = o / 48, c4 = o - pp * 48;
            float4 v;
            v.x = tS[pp * 193 + c4 * 4 + 0];
            v.y = tS[pp * 193 + c4 * 4 + 1];
            v.z = tS[pp * 193 + c4 * 4 + 2];
            v.w = tS[pp * 193 + c4 * 4 + 3];
            *(float4*)(xT + (size_t)(pix0 + pp) * 6144 + bc0 + c4 * 4) = v;
        }
    } else if (b < 6048) {
        // cores2/3 -> frag fp16 (f>=40 zero-padded)
        int gidx = (b - 2048) * 256 + tid;         // < 1024000
        int bb = gidx / 640;
        int o  = gidx - bb * 640;
        const float* src;
        _Float16* dst;
        if (bb < 1280) { src = c2 + (size_t)bb * 3200;          dst = Wh2 + (size_t)bb * 5120; }
        else           { src = c3 + (size_t)(bb - 1280) * 3200; dst = Wh3 + (size_t)(bb - 1280) * 5120; }
        int q  = o >> 6, l = o & 63;
        int ks = q / 5, nt = q - ks * 5;
        int c  = nt * 16 + (l & 15);
        int ul = c / 20;
        int v  = c - ul * 20;
        int f0 = ks * 32 + ((l >> 4) << 3);
        half8 hv;
        if (f0 < 40) {
            const float* sp = src + ul * 800 + f0 * 20 + v;
            #pragma unroll
            for (int j = 0; j < 8; ++j) hv[j] = (_Float16)sp[j * 20];
        } else {
            #pragma unroll
            for (int j = 0; j < 8; ++j) hv[j] = (_Float16)0.f;
        }
        *(half8*)(dst + (size_t)o * 8) = hv;
    } else if (b < 6384) {
        const int bb = b - 6048;
        const float* lb;
        float* ov;
        if (bb < 256)      { lb = l1 + (size_t)bb * 8000;         ov = v1 + bb * 400; }
        else if (bb < 320) { lb = l2 + (size_t)(bb - 256) * 8000; ov = v2 + (bb - 256) * 400; }
        else               { lb = l3 + (size_t)(bb - 320) * 8000; ov = v3 + (bb - 320) * 400; }
        for (int i = tid; i < 400; i += 256) {
            const float4* s = (const float4*)(lb + i * 20);
            float acc = 0.f;
            #pragma unroll
            for (int t = 0; t < 5; ++t) {
                float4 w = s[t];
                acc += w.x + w.y + w.z + w.w;
            }
            ov[i] = acc * VB;
        }
    } else {
        for (int i = tid; i < 672; i += 256) gzero[i] = 0.f;
    }
}

// ---------------------------------------------------------------------------
// Fused stage 1 with INLINE W conversion (no Wh1). Grid (256 p, 2 bh) x 256.
// Per lane: gather its B-frag's 8 fp32 at stride 20 from cores1, cvt fp16.
// Gather index math == verified wconv1 bijection. Two float[5][8] register
// buffers double-buffer the 3 K-groups per chunk (load g+1 || MFMA g).
// ---------------------------------------------------------------------------
#define LOADG(DST, BASE, KSOFF)                                               \
    {                                                                         \
        _Pragma("unroll")                                                     \
        for (int nt = 0; nt < 5; ++nt) {                                      \
            const float* sp_ = (BASE) + offnt[nt] + hoff + (KSOFF);           \
            _Pragma("unroll")                                                 \
            for (int j = 0; j < 8; ++j) DST[nt][j] = sp_[j * 20];             \
        }                                                                     \
    }

#define GRPMFMA(SRC, ksv)                                                     \
    {                                                                         \
        _Pragma("unroll")                                                     \
        for (int nt = 0; nt < 5; ++nt) {                                      \
            half8 cb;                                                         \
            _Pragma("unroll")                                                 \
            for (int j = 0; j < 8; ++j) cb[j] = (_Float16)SRC[nt][j];         \
            acc[nt] = __builtin_amdgcn_mfma_f32_16x16x32_f16(af[ksv], cb, acc[nt], 0, 0, 0); \
        }                                                                     \
    }

#define CHUNK1(ucv, P, Q, ISLAST)                                             \
    {                                                                         \
        const float* wc = wn + (ucv) * 7680;                                  \
        f32x4 acc[5];                                                         \
        _Pragma("unroll")                                                     \
        for (int nt = 0; nt < 5; ++nt) acc[nt] = (f32x4){0.f, 0.f, 0.f, 0.f}; \
        LOADG(Q, wc, 640)                                                     \
        GRPMFMA(P, 0)                                                         \
        LOADG(P, wc, 1280)                                                    \
        GRPMFMA(Q, 1)                                                         \
        if (!(ISLAST)) { LOADG(Q, wc + 7680, 0) }                             \
        GRPMFMA(P, 2)                                                         \
        _Pragma("unroll")                                                     \
        for (int nt = 0; nt < 5; ++nt) {                                      \
            _Pragma("unroll")                                                 \
            for (int r = 0; r < 4; ++r)                                       \
                Mw[(hi * 4 + r) * 84 + nt * 16 + row16] = acc[nt][r];         \
        }                                                                     \
        WAVEBAR();                                                            \
        _Pragma("unroll")                                                     \
        for (int ul = 0; ul < 4; ++ul) {                                      \
            float lvx = lw[bQ * 20 + (ucv) * 4 + ul];                         \
            _Pragma("unroll")                                                 \
            for (int j = 0; j < 5; ++j)                                       \
                lacc[j] += lvx * Mw[bQ * 84 + ul * 20 + mh * 5 + j];          \
        }                                                                     \
        WAVEBAR();                                                            \
    }

__global__ __launch_bounds__(256, 2)
void fused1_kernel(const float* __restrict__ xT, const float* __restrict__ cores1,
                   const float* __restrict__ labv,
                   float* __restrict__ z1, float* __restrict__ gs, float* __restrict__ gq)
{
    __shared__ __align__(16) float xS[4 * 768];
    __shared__ __align__(16) float MchunkS[4 * 16 * 84];
    __shared__ __align__(16) float leftS[4 * 320];

    const int tid = threadIdx.x;
    const int p   = blockIdx.x;
    const int bh  = blockIdx.y;
    const int wv  = tid >> 6, l = tid & 63;
    float* xSw = xS + wv * 768;
    float* Mw  = MchunkS + wv * 1344;
    float* lw  = leftS + wv * 320;
    const int row16 = l & 15, hi = l >> 4;
    const int bQ = l >> 2,   mh = l & 3;
    const int hh  = (p >> 7) * 16 + ((p >> 2) & 15);
    const int ww0 = ((p >> 6) & 1) * 16 + (p & 3) * 4;

    // per-lane gather offsets (verified wconv1 bijection)
    int offnt[5];
    #pragma unroll
    for (int nt = 0; nt < 5; ++nt) {
        int c = nt * 16 + row16;
        int ul = c / 20;
        offnt[nt] = ul * 1920 + (c - ul * 20);
    }
    const int hoff = hi * 160;   // (hi*8)*20

    #pragma unroll
    for (int j = 0; j < 5; ++j) lw[bQ * 20 + mh * 5 + j] = VB;
    WAVEBAR();

    float lacc[5] = {0.f, 0.f, 0.f, 0.f, 0.f};
    float rA[5][8], rB[5][8];

    #pragma unroll 1
    for (int n = 0; n < 4; ++n) {
        const float* wn = cores1 + (size_t)(p * 4 + n) * 38400;
        LOADG(rA, wn, 0)   // prologue: (uc=0, ks=0)

        const float* xsl = xT + (size_t)(hh * 32 + ww0 + n) * 6144 + bh * 3072 + wv * 768;
        #pragma unroll
        for (int k = 0; k < 3; ++k) {
            float4 v = *(const float4*)(xsl + (l + k * 64) * 4);
            *(float4*)&xSw[(l + k * 64) * 4] = v;
        }
        WAVEBAR();
        half8 af[3];
        #pragma unroll
        for (int ks = 0; ks < 3; ++ks) {
            int f0 = ks * 32 + hi * 8;
            int cc = (f0 < 48) ? f0 : f0 - 48;
            float4 a  = *(const float4*)&xSw[row16 * 48 + cc];
            float4 b2 = *(const float4*)&xSw[row16 * 48 + cc + 4];
            float vv[8] = {a.x, a.y, a.z, a.w, b2.x, b2.y, b2.z, b2.w};
            bool inv = (f0 >= 48);
            half8 hv;
            #pragma unroll
            for (int j = 0; j < 8; ++j) hv[j] = (_Float16)(inv ? (1.f - vv[j]) : vv[j]);
            af[ks] = hv;
        }
        WAVEBAR();

        CHUNK1(0, rA, rB, 0)
        CHUNK1(1, rB, rA, 0)
        CHUNK1(2, rA, rB, 0)
        CHUNK1(3, rB, rA, 0)
        CHUNK1(4, rA, rB, 1)

        #pragma unroll
        for (int j = 0; j < 5; ++j) { lw[bQ * 20 + mh * 5 + j] = lacc[j]; lacc[j] = 0.f; }
        WAVEBAR();
    }

    const float* lvp = labv + p * 400;
    #pragma unroll
    for (int k = 0; k < 7; ++k) { int i = l + k * 64; if (i < 400) Mw[i] = lvp[i]; }
    WAVEBAR();
    float yv[5] = {0.f, 0.f, 0.f, 0.f, 0.f};
    #pragma unroll
    for (int u = 0; u < 20; ++u) {
        float lu = lw[bQ * 20 + u];
        #pragma unroll
        for (int j = 0; j < 5; ++j) yv[j] += lu * Mw[u * 20 + mh * 5 + j];
    }
    float s = 0.f, s2 = 0.f;
    #pragma unroll
    for (int j = 0; j < 5; ++j) {
        z1[(size_t)(bh * 64 + wv * 16 + bQ) * 5120 + p * 20 + mh * 5 + j] = yv[j];
        s += yv[j]; s2 += yv[j] * yv[j];
    }
    #pragma unroll
    for (int off = 32; off > 0; off >>= 1) {
        s  += __shfl_down(s, off);
        s2 += __shfl_down(s2, off);
    }
    if (l == 0) { atomicAdd(&gs[p], s); atomicAdd(&gq[p], s2); }
}

// ---------------------------------------------------------------------------
// Fused stages 2 & 3 (verified R7-R10, unchanged)
// ---------------------------------------------------------------------------
#define UCBODYN(ucv, CUR, NXT)                                                   \
    {                                                                            \
        if ((ucv) < 4) {                                                         \
            const _Float16* bptr = whp + (size_t)((ucv) + 1) * 5120;             \
            _Pragma("unroll")                                                    \
            for (int q = 0; q < 10; ++q)                                         \
                NXT[q] = *(const half8*)(bptr + (q * 64 + l) * 8);               \
        }                                                                        \
        f32x4 acc[5];                                                            \
        _Pragma("unroll")                                                        \
        for (int nt = 0; nt < 5; ++nt) acc[nt] = (f32x4){0.f, 0.f, 0.f, 0.f};    \
        _Pragma("unroll")                                                        \
        for (int ks = 0; ks < 2; ++ks) {                                         \
            _Pragma("unroll")                                                    \
            for (int nt = 0; nt < 5; ++nt)                                       \
                acc[nt] = __builtin_amdgcn_mfma_f32_16x16x32_f16(                \
                    af[ks], CUR[ks * 5 + nt], acc[nt], 0, 0, 0);                 \
        }                                                                        \
        _Pragma("unroll")                                                        \
        for (int nt = 0; nt < 5; ++nt) {                                         \
            _Pragma("unroll")                                                    \
            for (int r = 0; r < 4; ++r)                                          \
                Mw[(hi * 4 + r) * 84 + nt * 16 + row16] = acc[nt][r];            \
        }                                                                        \
        WAVEBAR();                                                               \
        _Pragma("unroll")                                                        \
        for (int ul = 0; ul < 4; ++ul) {                                         \
            float lvx = lw[bQ * 20 + (ucv) * 4 + ul];                            \
            _Pragma("unroll")                                                    \
            for (int j = 0; j < 5; ++j)                                          \
                lacc[j] += lvx * Mw[bQ * 84 + ul * 20 + mh * 5 + j];             \
        }                                                                        \
        WAVEBAR();                                                               \
    }

template <int STAGE>
__global__ __launch_bounds__(256, 2)
void fusedN_kernel(const float* __restrict__ zin, const _Float16* __restrict__ Wh,
                   const float* __restrict__ labv,
                   const float* __restrict__ gsin, const float* __restrict__ gqin,
                   const float* __restrict__ gam,  const float* __restrict__ bet,
                   float* __restrict__ zout,
                   float* __restrict__ gsout, float* __restrict__ gqout)
{
    constexpr int ZIN  = (STAGE == 2) ? 5120 : 1280;
    constexpr int ZOUT = (STAGE == 2) ? 1280 : 320;
    constexpr int JUMP = (STAGE == 2) ? 256 : 64;

    __shared__ __align__(16) float zS[4 * 320];
    __shared__ float scS[4 * 20], shS[4 * 20];
    __shared__ __align__(16) float MchunkS[4 * 16 * 84];
    __shared__ __align__(16) float leftS[4 * 320];

    const int tid = threadIdx.x;
    const int p   = blockIdx.x;
    const int bh  = blockIdx.y;
    const int wv  = tid >> 6, l = tid & 63;
    float* zSw = zS + wv * 320;
    float* scw = scS + wv * 20;
    float* shw = shS + wv * 20;
    float* Mw  = MchunkS + wv * 1344;
    float* lw  = leftS + wv * 320;
    const int row16 = l & 15, hi = l >> 4;
    const int bQ = l >> 2,   mh = l & 3;
    const int bg = bh * 64;

    #pragma unroll
    for (int j = 0; j < 5; ++j) lw[bQ * 20 + mh * 5 + j] = VB;
    WAVEBAR();

    float lacc[5] = {0.f, 0.f, 0.f, 0.f, 0.f};

    #pragma unroll 1
    for (int n = 0; n < 4; ++n) {
        int hh, ww;
        if (STAGE == 2) { hh = (p >> 5) * 8 + ((p >> 1) & 7); ww = ((p >> 4) & 1) * 8 + (p & 1) * 4 + n; }
        else            { hh = (p >> 3) * 4 + (p & 3);        ww = ((p >> 2) & 1) * 4 + n; }
        const int oo = (STAGE == 2) ? (hh * 16 + ww) : (hh * 8 + ww);

        if (l < 20) {
            int ch = (l * JUMP + oo) / 20;
            float mean = gsin[ch] * (1.f / 2560.f);
            float var  = gqin[ch] * (1.f / 2560.f) - mean * mean;
            float rstd = rsqrtf(var + 1e-5f);
            float sc = gam[ch] * rstd;
            scw[l] = sc;
            shw[l] = bet[ch] - mean * sc;
        }
        WAVEBAR();
        #pragma unroll
        for (int q = 0; q < 5; ++q) {
            int d = hi * 5 + q;
            float zraw = zin[(size_t)(bg + wv * 16 + row16) * ZIN + d * JUMP + oo];
            zSw[row16 * 20 + d] = zraw * scw[d] + shw[d];
        }
        WAVEBAR();
        half8 af[2];
        #pragma unroll
        for (int ks = 0; ks < 2; ++ks) {
            int f0 = ks * 32 + hi * 8;
            half8 hv;
            #pragma unroll
            for (int j = 0; j < 8; ++j) {
                int f = f0 + j;
                float val;
                if (f < 20)      val = zSw[row16 * 20 + f];
                else if (f < 40) val = 1.f - zSw[row16 * 20 + f - 20];
                else             val = 0.f;
                hv[j] = (_Float16)val;
            }
            af[ks] = hv;
        }
        WAVEBAR();

        const _Float16* whp = Wh + (size_t)((p * 4 + n) * 5) * 5120;
        half8 bA[10], bB[10];
        {
            #pragma unroll
            for (int q = 0; q < 10; ++q) bA[q] = *(const half8*)(whp + (q * 64 + l) * 8);
        }
        UCBODYN(0, bA, bB)
        UCBODYN(1, bB, bA)
        UCBODYN(2, bA, bB)
        UCBODYN(3, bB, bA)
        UCBODYN(4, bA, bB)

        #pragma unroll
        for (int j = 0; j < 5; ++j) { lw[bQ * 20 + mh * 5 + j] = lacc[j]; lacc[j] = 0.f; }
        WAVEBAR();
    }

    const float* lvp = labv + p * 400;
    #pragma unroll
    for (int k = 0; k < 7; ++k) { int i = l + k * 64; if (i < 400) Mw[i] = lvp[i]; }
    WAVEBAR();
    float yv[5] = {0.f, 0.f, 0.f, 0.f, 0.f};
    #pragma unroll
    for (int u = 0; u < 20; ++u) {
        float lu = lw[bQ * 20 + u];
        #pragma unroll
        for (int j = 0; j < 5; ++j) yv[j] += lu * Mw[u * 20 + mh * 5 + j];
    }
    float s = 0.f, s2 = 0.f;
    #pragma unroll
    for (int j = 0; j < 5; ++j) {
        zout[(size_t)(bg + wv * 16 + bQ) * ZOUT + p * 20 + mh * 5 + j] = yv[j];
        s += yv[j]; s2 += yv[j] * yv[j];
    }
    #pragma unroll
    for (int off = 32; off > 0; off >>= 1) {
        s  += __shfl_down(s, off);
        s2 += __shfl_down(s2, off);
    }
    if (l == 0) { atomicAdd(&gsout[p], s); atomicAdd(&gqout[p], s2); }
}

// ---------------------------------------------------------------------------
// Final MPS (verified R8-R10)
// ---------------------------------------------------------------------------
__global__ __launch_bounds__(256, 4)
void final_kernel(const float* __restrict__ z3,
                  const float* __restrict__ coresF,
                  const float* __restrict__ labelF,
                  const float* __restrict__ g3,
                  const float* __restrict__ b3,
                  const float* __restrict__ gsum3,
                  const float* __restrict__ gsq3,
                  float* __restrict__ out)
{
    __shared__ __align__(16) float fS[16 * 40];
    __shared__ __align__(16) float MS[16 * 400];
    __shared__ float lvS[200];
    __shared__ float scS[16], shS[16];
    __shared__ float leftS[20];

    const int b   = blockIdx.x;
    const int tid = threadIdx.x;

    if (tid < 16) {
        float mean = gsum3[tid] * (1.f / 2560.f);
        float var  = gsq3[tid] * (1.f / 2560.f) - mean * mean;
        float rstd = rsqrtf(var + 1e-5f);
        float sc   = g3[tid] * rstd;
        scS[tid] = sc;
        shS[tid] = b3[tid] - mean * sc;
    }
    __syncthreads();

    for (int i = tid; i < 640; i += 256) {
        int n = i / 40, f = i - n * 40;
        float raw = z3[(size_t)b * 320 + n * 20 + (f % 20)];
        float val = raw * scS[n] + shS[n];
        fS[i] = (f < 20) ? val : (1.f - val);
    }
    for (int i = tid; i < 200; i += 256) {
        int u = i / 10, o = i - u * 10;
        const float* lb = labelF + (size_t)(u * 10 + o) * 20;
        float s = 0.f;
        #pragma unroll
        for (int vv = 0; vv < 20; ++vv) s += lb[vv];
        lvS[i] = s * VB;
    }
    __syncthreads();

    for (int i = tid; i < 6400; i += 256) {
        int n = i / 400, uv = i - n * 400;
        int u = uv / 20, v = uv - u * 20;
        const float* wb = coresF + ((size_t)(n * 20 + u) * 40) * 20 + v;
        const float* fb = fS + n * 40;
        float acc = 0.f;
        #pragma unroll
        for (int f = 0; f < 40; ++f) acc += fb[f] * wb[f * 20];
        MS[i] = acc;
    }
    __syncthreads();

    if (tid < 64) {
        if (tid < 20) leftS[tid] = VB;
        WAVEBAR();
        #pragma unroll 1
        for (int n = 0; n < 16; ++n) {
            float tmp = 0.f;
            if (tid < 20) {
                #pragma unroll
                for (int u = 0; u < 20; ++u) tmp += leftS[u] * MS[n * 400 + u * 20 + tid];
            }
            WAVEBAR();
            if (tid < 20) leftS[tid] = tmp;
            WAVEBAR();
        }
        if (tid < 10) {
            float s = 0.f;
            #pragma unroll
            for (int u = 0; u < 20; ++u) s += leftS[u] * lvS[u * 10 + tid];
            out[b * 10 + tid] = s;
        }
    }
}

// ---------------------------------------------------------------------------
extern "C" void kernel_launch(void* const* d_in, const int* in_sizes, int n_in,
                              void* d_out, int out_size, void* d_ws, size_t ws_size,
                              hipStream_t stream)
{
    const float* x      = (const float*)d_in[0];
    const float* cores1 = (const float*)d_in[1];
    const float* label1 = (const float*)d_in[2];
    const float* g1     = (const float*)d_in[3];
    const float* b1     = (const float*)d_in[4];
    const float* cores2 = (const float*)d_in[5];
    const float* label2 = (const float*)d_in[6];
    const float* g2     = (const float*)d_in[7];
    const float* b2     = (const float*)d_in[8];
    const float* cores3 = (const float*)d_in[9];
    const float* label3 = (const float*)d_in[10];
    const float* g3     = (const float*)d_in[11];
    const float* b3     = (const float*)d_in[12];
    const float* coresF = (const float*)d_in[13];
    const float* labelF = (const float*)d_in[14];

    float* ws  = (float*)d_ws;
    float* z1  = ws + Z1_OFF;
    float* z2  = ws + Z2_OFF;
    float* z3  = ws + Z3_OFF;
    float* gs1 = ws + GS1_OFF; float* gq1 = ws + GQ1_OFF;
    float* gs2 = ws + GS2_OFF; float* gq2 = ws + GQ2_OFF;
    float* gs3 = ws + GS3_OFF; float* gq3 = ws + GQ3_OFF;
    float* lv1 = ws + LV1_OFF;
    float* lv2 = ws + LV2_OFF;
    float* lv3 = ws + LV3_OFF;
    float* xT  = ws + XT_OFF;
    _Float16* Wh2 = (_Float16*)(ws + WH2_OFF);
    _Float16* Wh3 = (_Float16*)(ws + WH3_OFF);

    prep_kernel<<<6385, 256, 0, stream>>>(x, cores2, cores3,
                                          label1, label2, label3,
                                          xT, Wh2, Wh3,
                                          lv1, lv2, lv3, gs1);

    fused1_kernel<<<dim3(256, 2), 256, 0, stream>>>(xT, cores1, lv1, z1, gs1, gq1);
    fusedN_kernel<2><<<dim3(64, 2), 256, 0, stream>>>(z1, Wh2, lv2, gs1, gq1, g1, b1,
                                                      z2, gs2, gq2);
    fusedN_kernel<3><<<dim3(16, 2), 256, 0, stream>>>(z2, Wh3, lv3, gs2, gq2, g2, b2,
                                                      z3, gs3, gq3);
    final_kernel<<<128, 256, 0, stream>>>(z3, coresF, labelF, g3, b3,
                                          gs3, gq3, (float*)d_out);
}

// Round 12
// 123.747 us; speedup vs baseline: 1.2989x; 1.1692x over previous
//
#include <hip/hip_runtime.h>

#define VB 0.22360679774997896f  // 20^-0.5

typedef __attribute__((ext_vector_type(8))) _Float16 half8;
typedef __attribute__((ext_vector_type(4))) float f32x4;

// workspace float offsets
#define Z1_OFF   0
#define Z2_OFF   655360
#define Z3_OFF   819200
#define GS1_OFF  860160
#define GQ1_OFF  860416
#define GS2_OFF  860672
#define GQ2_OFF  860736
#define GS3_OFF  860800
#define GQ3_OFF  860816
#define LV1_OFF  860832    // 256*400
#define LV2_OFF  963232    // 64*400
#define LV3_OFF  988832    // 16*400
#define XT_OFF   995232    // 1024*6144 = 6291456 floats
#define WH2_OFF  7286688   // 6553600 halfs = 3276800 floats
#define WH3_OFF  10563488  // 1638400 halfs = 819200 floats

#define WAVEBAR() __builtin_amdgcn_wave_barrier()

// ---------------------------------------------------------------------------
// Merged prep (unchanged from R11 pass). Grid 6385 x 256.
// ---------------------------------------------------------------------------
__global__ __launch_bounds__(256, 8)
void prep_kernel(const float* __restrict__ x,
                 const float* __restrict__ c2, const float* __restrict__ c3,
                 const float* __restrict__ l1, const float* __restrict__ l2,
                 const float* __restrict__ l3,
                 float* __restrict__ xT,
                 _Float16* __restrict__ Wh2, _Float16* __restrict__ Wh3,
                 float* __restrict__ v1, float* __restrict__ v2,
                 float* __restrict__ v3,
                 float* __restrict__ gzero)
{
    __shared__ __align__(16) float tS[16 * 193];
    const int tid = threadIdx.x;
    const int b   = blockIdx.x;

    if (b < 2048) {
        const int pix0 = (b & 63) * 16;
        const int bc0  = (b >> 6) * 192;
        #pragma unroll
        for (int k = 0; k < 3; ++k) {
            int i = tid + k * 256;
            int r = i >> 2, q = i & 3;
            float4 v = *(const float4*)(x + (size_t)(bc0 + r) * 1024 + pix0 + q * 4);
            tS[(q * 4 + 0) * 193 + r] = v.x;
            tS[(q * 4 + 1) * 193 + r] = v.y;
            tS[(q * 4 + 2) * 193 + r] = v.z;
            tS[(q * 4 + 3) * 193 + r] = v.w;
        }
        __syncthreads();
        #pragma unroll
        for (int k = 0; k < 3; ++k) {
            int o = tid + k * 256;
            int pp = o / 48, c4 = o - pp * 48;
            float4 v;
            v.x = tS[pp * 193 + c4 * 4 + 0];
            v.y = tS[pp * 193 + c4 * 4 + 1];
            v.z = tS[pp * 193 + c4 * 4 + 2];
            v.w = tS[pp * 193 + c4 * 4 + 3];
            *(float4*)(xT + (size_t)(pix0 + pp) * 6144 + bc0 + c4 * 4) = v;
        }
    } else if (b < 6048) {
        int gidx = (b - 2048) * 256 + tid;
        int bb = gidx / 640;
        int o  = gidx - bb * 640;
        const float* src;
        _Float16* dst;
        if (bb < 1280) { src = c2 + (size_t)bb * 3200;          dst = Wh2 + (size_t)bb * 5120; }
        else           { src = c3 + (size_t)(bb - 1280) * 3200; dst = Wh3 + (size_t)(bb - 1280) * 5120; }
        int q  = o >> 6, l = o & 63;
        int ks = q / 5, nt = q - ks * 5;
        int c  = nt * 16 + (l & 15);
        int ul = c / 20;
        int v  = c - ul * 20;
        int f0 = ks * 32 + ((l >> 4) << 3);
        half8 hv;
        if (f0 < 40) {
            const float* sp = src + ul * 800 + f0 * 20 + v;
            #pragma unroll
            for (int j = 0; j < 8; ++j) hv[j] = (_Float16)sp[j * 20];
        } else {
            #pragma unroll
            for (int j = 0; j < 8; ++j) hv[j] = (_Float16)0.f;
        }
        *(half8*)(dst + (size_t)o * 8) = hv;
    } else if (b < 6384) {
        const int bb = b - 6048;
        const float* lb;
        float* ov;
        if (bb < 256)      { lb = l1 + (size_t)bb * 8000;         ov = v1 + bb * 400; }
        else if (bb < 320) { lb = l2 + (size_t)(bb - 256) * 8000; ov = v2 + (bb - 256) * 400; }
        else               { lb = l3 + (size_t)(bb - 320) * 8000; ov = v3 + (bb - 320) * 400; }
        for (int i = tid; i < 400; i += 256) {
            const float4* s = (const float4*)(lb + i * 20);
            float acc = 0.f;
            #pragma unroll
            for (int t = 0; t < 5; ++t) {
                float4 w = s[t];
                acc += w.x + w.y + w.z + w.w;
            }
            ov[i] = acc * VB;
        }
    } else {
        for (int i = tid; i < 672; i += 256) gzero[i] = 0.f;
    }
}

// ---------------------------------------------------------------------------
// Fused stage 1, staged-coalesced variant:
//  - block stages each 30 KB W chunk with 8 contiguous float4/thread
//    (issued one full compute-phase early)
//  - scatter to LDS fp16 frag buffer via PRECOMPUTED chunk-invariant addrs
//    (R8-verified bijection), double-buffered (2 x 15 KB)
//  - MFMA B-operands read as contiguous half8 ds_read_b128
//  - chain/left/epilogue identical to verified R7-R11 code
// ---------------------------------------------------------------------------
#define CHUNKX(ucv, LAST)                                                     \
    {                                                                         \
        if (!(LAST)) {                                                        \
            _Pragma("unroll")                                                 \
            for (int k = 0; k < 8; ++k) {                                     \
                int i4 = tid + k * 256;                                       \
                if (i4 < 1920) wr[k] = *(const float4*)(wnext + i4 * 4);      \
            }                                                                 \
            wnext += 7680;                                                    \
        }                                                                     \
        f32x4 acc[5];                                                         \
        _Pragma("unroll")                                                     \
        for (int nt = 0; nt < 5; ++nt) acc[nt] = (f32x4){0.f, 0.f, 0.f, 0.f};\
        _Pragma("unroll")                                                     \
        for (int ks = 0; ks < 3; ++ks) {                                      \
            _Pragma("unroll")                                                 \
            for (int nt = 0; nt < 5; ++nt) {                                  \
                half8 bf = *(const half8*)&Fcur[((ks * 5 + nt) * 64 + l) * 8];\
                acc[nt] = __builtin_amdgcn_mfma_f32_16x16x32_f16(             \
                    af[ks], bf, acc[nt], 0, 0, 0);                            \
            }                                                                 \
        }                                                                     \
        _Pragma("unroll")                                                     \
        for (int nt = 0; nt < 5; ++nt) {                                      \
            _Pragma("unroll")                                                 \
            for (int r = 0; r < 4; ++r)                                       \
                Mw[(hi * 4 + r) * 84 + nt * 16 + row16] = acc[nt][r];         \
        }                                                                     \
        WAVEBAR();                                                            \
        _Pragma("unroll")                                                     \
        for (int ul = 0; ul < 4; ++ul) {                                      \
            float lvx = lw[bQ * 20 + (ucv) * 4 + ul];                         \
            _Pragma("unroll")                                                 \
            for (int j = 0; j < 5; ++j)                                       \
                lacc[j] += lvx * Mw[bQ * 84 + ul * 20 + mh * 5 + j];          \
        }                                                                     \
        WAVEBAR();                                                            \
        __syncthreads();                                                      \
        if (!(LAST)) {                                                        \
            _Pragma("unroll")                                                 \
            for (int k = 0; k < 8; ++k) {                                     \
                int i4 = tid + k * 256;                                       \
                if (i4 < 1920) {                                              \
                    float vals[4] = {wr[k].x, wr[k].y, wr[k].z, wr[k].w};     \
                    _Pragma("unroll")                                         \
                    for (int t = 0; t < 4; ++t)                               \
                        Fnxt[sAddr[k][t]] = (_Float16)vals[t];                \
                }                                                             \
            }                                                                 \
        }                                                                     \
        __syncthreads();                                                      \
        { _Float16* t_ = Fcur; Fcur = Fnxt; Fnxt = t_; }                      \
    }

__global__ __launch_bounds__(256, 2)
void fused1_kernel(const float* __restrict__ xT, const float* __restrict__ cores1,
                   const float* __restrict__ labv,
                   float* __restrict__ z1, float* __restrict__ gs, float* __restrict__ gq)
{
    __shared__ __align__(16) float xS[4 * 768];          // 12288 B
    __shared__ __align__(16) _Float16 Fbuf[2][7680];     // 30720 B
    __shared__ __align__(16) float MchunkS[4 * 16 * 84]; // 21504 B
    __shared__ __align__(16) float leftS[4 * 320];       // 5120 B

    const int tid = threadIdx.x;
    const int p   = blockIdx.x;
    const int bh  = blockIdx.y;
    const int wv  = tid >> 6, l = tid & 63;
    float* xSw = xS + wv * 768;
    float* Mw  = MchunkS + wv * 1344;
    float* lw  = leftS + wv * 320;
    const int row16 = l & 15, hi = l >> 4;
    const int bQ = l >> 2,   mh = l & 3;
    const int hh  = (p >> 7) * 16 + ((p >> 2) & 15);
    const int ww0 = ((p >> 6) & 1) * 16 + (p & 3) * 4;

    // chunk-invariant scatter addresses (R8-verified bijection)
    int sAddr[8][4];
    #pragma unroll
    for (int k = 0; k < 8; ++k) {
        int i4 = tid + k * 256;
        if (i4 < 1920) {
            #pragma unroll
            for (int t = 0; t < 4; ++t) {
                int e = i4 * 4 + t;
                int v = e % 20;
                int r = e / 20;
                int f = r % 96;
                int ul = r / 96;
                int c = ul * 20 + v;
                sAddr[k][t] = (((f >> 5) * 5 + (c >> 4)) * 64 +
                               ((f >> 3) & 3) * 16 + (c & 15)) * 8 + (f & 7);
            }
        }
    }

    #pragma unroll
    for (int j = 0; j < 5; ++j) lw[bQ * 20 + mh * 5 + j] = VB;
    WAVEBAR();

    float lacc[5] = {0.f, 0.f, 0.f, 0.f, 0.f};
    float4 wr[8];
    const float* wnext = cores1 + (size_t)p * 153600;

    // prologue: load + scatter chunk 0 into Fbuf[0]
    #pragma unroll
    for (int k = 0; k < 8; ++k) {
        int i4 = tid + k * 256;
        if (i4 < 1920) wr[k] = *(const float4*)(wnext + i4 * 4);
    }
    wnext += 7680;
    _Float16* Fcur = &Fbuf[0][0];
    _Float16* Fnxt = &Fbuf[1][0];
    #pragma unroll
    for (int k = 0; k < 8; ++k) {
        int i4 = tid + k * 256;
        if (i4 < 1920) {
            float vals[4] = {wr[k].x, wr[k].y, wr[k].z, wr[k].w};
            #pragma unroll
            for (int t = 0; t < 4; ++t)
                Fcur[sAddr[k][t]] = (_Float16)vals[t];
        }
    }
    __syncthreads();

    #pragma unroll 1
    for (int n = 0; n < 4; ++n) {
        // x slab -> wave-private LDS, build A-frags
        const float* xsl = xT + (size_t)(hh * 32 + ww0 + n) * 6144 + bh * 3072 + wv * 768;
        #pragma unroll
        for (int k = 0; k < 3; ++k) {
            float4 v = *(const float4*)(xsl + (l + k * 64) * 4);
            *(float4*)&xSw[(l + k * 64) * 4] = v;
        }
        WAVEBAR();
        half8 af[3];
        #pragma unroll
        for (int ks = 0; ks < 3; ++ks) {
            int f0 = ks * 32 + hi * 8;
            int cc = (f0 < 48) ? f0 : f0 - 48;
            float4 a  = *(const float4*)&xSw[row16 * 48 + cc];
            float4 b2 = *(const float4*)&xSw[row16 * 48 + cc + 4];
            float vv[8] = {a.x, a.y, a.z, a.w, b2.x, b2.y, b2.z, b2.w};
            bool inv = (f0 >= 48);
            half8 hv;
            #pragma unroll
            for (int j = 0; j < 8; ++j) hv[j] = (_Float16)(inv ? (1.f - vv[j]) : vv[j]);
            af[ks] = hv;
        }
        WAVEBAR();

        const bool last = (n == 3);
        CHUNKX(0, 0)
        CHUNKX(1, 0)
        CHUNKX(2, 0)
        CHUNKX(3, 0)
        CHUNKX(4, last)

        #pragma unroll
        for (int j = 0; j < 5; ++j) { lw[bQ * 20 + mh * 5 + j] = lacc[j]; lacc[j] = 0.f; }
        WAVEBAR();
    }

    // epilogue: labv matvec + z1 + BN atomic sums (verified)
    const float* lvp = labv + p * 400;
    #pragma unroll
    for (int k = 0; k < 7; ++k) { int i = l + k * 64; if (i < 400) Mw[i] = lvp[i]; }
    WAVEBAR();
    float yv[5] = {0.f, 0.f, 0.f, 0.f, 0.f};
    #pragma unroll
    for (int u = 0; u < 20; ++u) {
        float lu = lw[bQ * 20 + u];
        #pragma unroll
        for (int j = 0; j < 5; ++j) yv[j] += lu * Mw[u * 20 + mh * 5 + j];
    }
    float s = 0.f, s2 = 0.f;
    #pragma unroll
    for (int j = 0; j < 5; ++j) {
        z1[(size_t)(bh * 64 + wv * 16 + bQ) * 5120 + p * 20 + mh * 5 + j] = yv[j];
        s += yv[j]; s2 += yv[j] * yv[j];
    }
    #pragma unroll
    for (int off = 32; off > 0; off >>= 1) {
        s  += __shfl_down(s, off);
        s2 += __shfl_down(s2, off);
    }
    if (l == 0) { atomicAdd(&gs[p], s); atomicAdd(&gq[p], s2); }
}

// ---------------------------------------------------------------------------
// Fused stages 2 & 3 (verified R7-R11, unchanged)
// ---------------------------------------------------------------------------
#define UCBODYN(ucv, CUR, NXT)                                                   \
    {                                                                            \
        if ((ucv) < 4) {                                                         \
            const _Float16* bptr = whp + (size_t)((ucv) + 1) * 5120;             \
            _Pragma("unroll")                                                    \
            for (int q = 0; q < 10; ++q)                                         \
                NXT[q] = *(const half8*)(bptr + (q * 64 + l) * 8);               \
        }                                                                        \
        f32x4 acc[5];                                                            \
        _Pragma("unroll")                                                        \
        for (int nt = 0; nt < 5; ++nt) acc[nt] = (f32x4){0.f, 0.f, 0.f, 0.f};    \
        _Pragma("unroll")                                                        \
        for (int ks = 0; ks < 2; ++ks) {                                         \
            _Pragma("unroll")                                                    \
            for (int nt = 0; nt < 5; ++nt)                                       \
                acc[nt] = __builtin_amdgcn_mfma_f32_16x16x32_f16(                \
                    af[ks], CUR[ks * 5 + nt], acc[nt], 0, 0, 0);                 \
        }                                                                        \
        _Pragma("unroll")                                                        \
        for (int nt = 0; nt < 5; ++nt) {                                         \
            _Pragma("unroll")                                                    \
            for (int r = 0; r < 4; ++r)                                          \
                Mw[(hi * 4 + r) * 84 + nt * 16 + row16] = acc[nt][r];            \
        }                                                                        \
        WAVEBAR();                                                               \
        _Pragma("unroll")                                                        \
        for (int ul = 0; ul < 4; ++ul) {                                         \
            float lvx = lw[bQ * 20 + (ucv) * 4 + ul];                            \
            _Pragma("unroll")                                                    \
            for (int j = 0; j < 5; ++j)                                          \
                lacc[j] += lvx * Mw[bQ * 84 + ul * 20 + mh * 5 + j];             \
        }                                                                        \
        WAVEBAR();                                                               \
    }

template <int STAGE>
__global__ __launch_bounds__(256, 2)
void fusedN_kernel(const float* __restrict__ zin, const _Float16* __restrict__ Wh,
                   const float* __restrict__ labv,
                   const float* __restrict__ gsin, const float* __restrict__ gqin,
                   const float* __restrict__ gam,  const float* __restrict__ bet,
                   float* __restrict__ zout,
                   float* __restrict__ gsout, float* __restrict__ gqout)
{
    constexpr int ZIN  = (STAGE == 2) ? 5120 : 1280;
    constexpr int ZOUT = (STAGE == 2) ? 1280 : 320;
    constexpr int JUMP = (STAGE == 2) ? 256 : 64;

    __shared__ __align__(16) float zS[4 * 320];
    __shared__ float scS[4 * 20], shS[4 * 20];
    __shared__ __align__(16) float MchunkS[4 * 16 * 84];
    __shared__ __align__(16) float leftS[4 * 320];

    const int tid = threadIdx.x;
    const int p   = blockIdx.x;
    const int bh  = blockIdx.y;
    const int wv  = tid >> 6, l = tid & 63;
    float* zSw = zS + wv * 320;
    float* scw = scS + wv * 20;
    float* shw = shS + wv * 20;
    float* Mw  = MchunkS + wv * 1344;
    float* lw  = leftS + wv * 320;
    const int row16 = l & 15, hi = l >> 4;
    const int bQ = l >> 2,   mh = l & 3;
    const int bg = bh * 64;

    #pragma unroll
    for (int j = 0; j < 5; ++j) lw[bQ * 20 + mh * 5 + j] = VB;
    WAVEBAR();

    float lacc[5] = {0.f, 0.f, 0.f, 0.f, 0.f};

    #pragma unroll 1
    for (int n = 0; n < 4; ++n) {
        int hh, ww;
        if (STAGE == 2) { hh = (p >> 5) * 8 + ((p >> 1) & 7); ww = ((p >> 4) & 1) * 8 + (p & 1) * 4 + n; }
        else            { hh = (p >> 3) * 4 + (p & 3);        ww = ((p >> 2) & 1) * 4 + n; }
        const int oo = (STAGE == 2) ? (hh * 16 + ww) : (hh * 8 + ww);

        if (l < 20) {
            int ch = (l * JUMP + oo) / 20;
            float mean = gsin[ch] * (1.f / 2560.f);
            float var  = gqin[ch] * (1.f / 2560.f) - mean * mean;
            float rstd = rsqrtf(var + 1e-5f);
            float sc = gam[ch] * rstd;
            scw[l] = sc;
            shw[l] = bet[ch] - mean * sc;
        }
        WAVEBAR();
        #pragma unroll
        for (int q = 0; q < 5; ++q) {
            int d = hi * 5 + q;
            float zraw = zin[(size_t)(bg + wv * 16 + row16) * ZIN + d * JUMP + oo];
            zSw[row16 * 20 + d] = zraw * scw[d] + shw[d];
        }
        WAVEBAR();
        half8 af[2];
        #pragma unroll
        for (int ks = 0; ks < 2; ++ks) {
            int f0 = ks * 32 + hi * 8;
            half8 hv;
            #pragma unroll
            for (int j = 0; j < 8; ++j) {
                int f = f0 + j;
                float val;
                if (f < 20)      val = zSw[row16 * 20 + f];
                else if (f < 40) val = 1.f - zSw[row16 * 20 + f - 20];
                else             val = 0.f;
                hv[j] = (_Float16)val;
            }
            af[ks] = hv;
        }
        WAVEBAR();

        const _Float16* whp = Wh + (size_t)((p * 4 + n) * 5) * 5120;
        half8 bA[10], bB[10];
        {
            #pragma unroll
            for (int q = 0; q < 10; ++q) bA[q] = *(const half8*)(whp + (q * 64 + l) * 8);
        }
        UCBODYN(0, bA, bB)
        UCBODYN(1, bB, bA)
        UCBODYN(2, bA, bB)
        UCBODYN(3, bB, bA)
        UCBODYN(4, bA, bB)

        #pragma unroll
        for (int j = 0; j < 5; ++j) { lw[bQ * 20 + mh * 5 + j] = lacc[j]; lacc[j] = 0.f; }
        WAVEBAR();
    }

    const float* lvp = labv + p * 400;
    #pragma unroll
    for (int k = 0; k < 7; ++k) { int i = l + k * 64; if (i < 400) Mw[i] = lvp[i]; }
    WAVEBAR();
    float yv[5] = {0.f, 0.f, 0.f, 0.f, 0.f};
    #pragma unroll
    for (int u = 0; u < 20; ++u) {
        float lu = lw[bQ * 20 + u];
        #pragma unroll
        for (int j = 0; j < 5; ++j) yv[j] += lu * Mw[u * 20 + mh * 5 + j];
    }
    float s = 0.f, s2 = 0.f;
    #pragma unroll
    for (int j = 0; j < 5; ++j) {
        zout[(size_t)(bg + wv * 16 + bQ) * ZOUT + p * 20 + mh * 5 + j] = yv[j];
        s += yv[j]; s2 += yv[j] * yv[j];
    }
    #pragma unroll
    for (int off = 32; off > 0; off >>= 1) {
        s  += __shfl_down(s, off);
        s2 += __shfl_down(s2, off);
    }
    if (l == 0) { atomicAdd(&gsout[p], s); atomicAdd(&gqout[p], s2); }
}

// ---------------------------------------------------------------------------
// Final MPS (verified R8-R11)
// ---------------------------------------------------------------------------
__global__ __launch_bounds__(256, 4)
void final_kernel(const float* __restrict__ z3,
                  const float* __restrict__ coresF,
                  const float* __restrict__ labelF,
                  const float* __restrict__ g3,
                  const float* __restrict__ b3,
                  const float* __restrict__ gsum3,
                  const float* __restrict__ gsq3,
                  float* __restrict__ out)
{
    __shared__ __align__(16) float fS[16 * 40];
    __shared__ __align__(16) float MS[16 * 400];
    __shared__ float lvS[200];
    __shared__ float scS[16], shS[16];
    __shared__ float leftS[20];

    const int b   = blockIdx.x;
    const int tid = threadIdx.x;

    if (tid < 16) {
        float mean = gsum3[tid] * (1.f / 2560.f);
        float var  = gsq3[tid] * (1.f / 2560.f) - mean * mean;
        float rstd = rsqrtf(var + 1e-5f);
        float sc   = g3[tid] * rstd;
        scS[tid] = sc;
        shS[tid] = b3[tid] - mean * sc;
    }
    __syncthreads();

    for (int i = tid; i < 640; i += 256) {
        int n = i / 40, f = i - n * 40;
        float raw = z3[(size_t)b * 320 + n * 20 + (f % 20)];
        float val = raw * scS[n] + shS[n];
        fS[i] = (f < 20) ? val : (1.f - val);
    }
    for (int i = tid; i < 200; i += 256) {
        int u = i / 10, o = i - u * 10;
        const float* lb = labelF + (size_t)(u * 10 + o) * 20;
        float s = 0.f;
        #pragma unroll
        for (int vv = 0; vv < 20; ++vv) s += lb[vv];
        lvS[i] = s * VB;
    }
    __syncthreads();

    for (int i = tid; i < 6400; i += 256) {
        int n = i / 400, uv = i - n * 400;
        int u = uv / 20, v = uv - u * 20;
        const float* wb = coresF + ((size_t)(n * 20 + u) * 40) * 20 + v;
        const float* fb = fS + n * 40;
        float acc = 0.f;
        #pragma unroll
        for (int f = 0; f < 40; ++f) acc += fb[f] * wb[f * 20];
        MS[i] = acc;
    }
    __syncthreads();

    if (tid < 64) {
        if (tid < 20) leftS[tid] = VB;
        WAVEBAR();
        #pragma unroll 1
        for (int n = 0; n < 16; ++n) {
            float tmp = 0.f;
            if (tid < 20) {
                #pragma unroll
                for (int u = 0; u < 20; ++u) tmp += leftS[u] * MS[n * 400 + u * 20 + tid];
            }
            WAVEBAR();
            if (tid < 20) leftS[tid] = tmp;
            WAVEBAR();
        }
        if (tid < 10) {
            float s = 0.f;
            #pragma unroll
            for (int u = 0; u < 20; ++u) s += leftS[u] * lvS[u * 10 + tid];
            out[b * 10 + tid] = s;
        }
    }
}

// ---------------------------------------------------------------------------
extern "C" void kernel_launch(void* const* d_in, const int* in_sizes, int n_in,
                              void* d_out, int out_size, void* d_ws, size_t ws_size,
                              hipStream_t stream)
{
    const float* x      = (const float*)d_in[0];
    const float* cores1 = (const float*)d_in[1];
    const float* label1 = (const float*)d_in[2];
    const float* g1     = (const float*)d_in[3];
    const float* b1     = (const float*)d_in[4];
    const float* cores2 = (const float*)d_in[5];
    const float* label2 = (const float*)d_in[6];
    const float* g2     = (const float*)d_in[7];
    const float* b2     = (const float*)d_in[8];
    const float* cores3 = (const float*)d_in[9];
    const float* label3 = (const float*)d_in[10];
    const float* g3     = (const float*)d_in[11];
    const float* b3     = (const float*)d_in[12];
    const float* coresF = (const float*)d_in[13];
    const float* labelF = (const float*)d_in[14];

    float* ws  = (float*)d_ws;
    float* z1  = ws + Z1_OFF;
    float* z2  = ws + Z2_OFF;
    float* z3  = ws + Z3_OFF;
    float* gs1 = ws + GS1_OFF; float* gq1 = ws + GQ1_OFF;
    float* gs2 = ws + GS2_OFF; float* gq2 = ws + GQ2_OFF;
    float* gs3 = ws + GS3_OFF; float* gq3 = ws + GQ3_OFF;
    float* lv1 = ws + LV1_OFF;
    float* lv2 = ws + LV2_OFF;
    float* lv3 = ws + LV3_OFF;
    float* xT  = ws + XT_OFF;
    _Float16* Wh2 = (_Float16*)(ws + WH2_OFF);
    _Float16* Wh3 = (_Float16*)(ws + WH3_OFF);

    prep_kernel<<<6385, 256, 0, stream>>>(x, cores2, cores3,
                                          label1, label2, label3,
                                          xT, Wh2, Wh3,
                                          lv1, lv2, lv3, gs1);

    fused1_kernel<<<dim3(256, 2), 256, 0, stream>>>(xT, cores1, lv1, z1, gs1, gq1);
    fusedN_kernel<2><<<dim3(64, 2), 256, 0, stream>>>(z1, Wh2, lv2, gs1, gq1, g1, b1,
                                                      z2, gs2, gq2);
    fusedN_kernel<3><<<dim3(16, 2), 256, 0, stream>>>(z2, Wh3, lv3, gs2, gq2, g2, b2,
                                                      z3, gs3, gq3);
    final_kernel<<<128, 256, 0, stream>>>(z3, coresF, labelF, g3, b3,
                                          gs3, gq3, (float*)d_out);
}

// Round 13
// 113.040 us; speedup vs baseline: 1.4219x; 1.0947x over previous
//
#include <hip/hip_runtime.h>

#define VB 0.22360679774997896f  // 20^-0.5

typedef __attribute__((ext_vector_type(8))) _Float16 half8;
typedef __attribute__((ext_vector_type(4))) float f32x4;

// workspace float offsets
#define Z1_OFF   0
#define Z2_OFF   655360
#define Z3_OFF   819200
#define GS1_OFF  860160
#define GQ1_OFF  860416
#define GS2_OFF  860672
#define GQ2_OFF  860736
#define GS3_OFF  860800
#define GQ3_OFF  860816
#define LV1_OFF  860832    // 256*400
#define LV2_OFF  963232    // 64*400
#define LV3_OFF  988832    // 16*400
#define WH2_OFF  995232    // 6553600 halfs = 3276800 floats
#define WH3_OFF  4272032   // 1638400 halfs = 819200 floats

#define WAVEBAR() __builtin_amdgcn_wave_barrier()

// ---------------------------------------------------------------------------
// prep (xt ELIMINATED): grid 4337 x 256.
//   [0,4000)     : cores2/3 -> fp16 B-frag, flat 1 half8/thread
//   [4000,4336)  : label pre-contraction
//   4336         : zero BN atomic-sum region (stages 2/3 still atomics)
// ---------------------------------------------------------------------------
__global__ __launch_bounds__(256, 8)
void prep_kernel(const float* __restrict__ c2, const float* __restrict__ c3,
                 const float* __restrict__ l1, const float* __restrict__ l2,
                 const float* __restrict__ l3,
                 _Float16* __restrict__ Wh2, _Float16* __restrict__ Wh3,
                 float* __restrict__ v1, float* __restrict__ v2,
                 float* __restrict__ v3,
                 float* __restrict__ gzero)
{
    const int tid = threadIdx.x;
    const int b   = blockIdx.x;

    if (b < 4000) {
        int gidx = b * 256 + tid;                  // < 1024000
        int bb = gidx / 640;
        int o  = gidx - bb * 640;
        const float* src;
        _Float16* dst;
        if (bb < 1280) { src = c2 + (size_t)bb * 3200;          dst = Wh2 + (size_t)bb * 5120; }
        else           { src = c3 + (size_t)(bb - 1280) * 3200; dst = Wh3 + (size_t)(bb - 1280) * 5120; }
        int q  = o >> 6, l = o & 63;
        int ks = q / 5, nt = q - ks * 5;
        int c  = nt * 16 + (l & 15);
        int ul = c / 20;
        int v  = c - ul * 20;
        int f0 = ks * 32 + ((l >> 4) << 3);
        half8 hv;
        if (f0 < 40) {
            const float* sp = src + ul * 800 + f0 * 20 + v;
            #pragma unroll
            for (int j = 0; j < 8; ++j) hv[j] = (_Float16)sp[j * 20];
        } else {
            #pragma unroll
            for (int j = 0; j < 8; ++j) hv[j] = (_Float16)0.f;
        }
        *(half8*)(dst + (size_t)o * 8) = hv;
    } else if (b < 4336) {
        const int bb = b - 4000;
        const float* lb;
        float* ov;
        if (bb < 256)      { lb = l1 + (size_t)bb * 8000;         ov = v1 + bb * 400; }
        else if (bb < 320) { lb = l2 + (size_t)(bb - 256) * 8000; ov = v2 + (bb - 256) * 400; }
        else               { lb = l3 + (size_t)(bb - 320) * 8000; ov = v3 + (bb - 320) * 400; }
        for (int i = tid; i < 400; i += 256) {
            const float4* s = (const float4*)(lb + i * 20);
            float acc = 0.f;
            #pragma unroll
            for (int t = 0; t < 5; ++t) {
                float4 w = s[t];
                acc += w.x + w.y + w.z + w.w;
            }
            ov[i] = acc * VB;
        }
    } else {
        for (int i = tid; i < 672; i += 256) gzero[i] = 0.f;
    }
}

// ---------------------------------------------------------------------------
// Fused stage 1: ONE 512-thread block per patch (grid 256 = 1/CU, 8 waves x
// 16 batch rows). cores1 read ONCE. x read directly (float4 = 4 sites) into
// registers, per-site select into wave-private xS. W chunk staged coalesced
// + LDS fp16 scatter (R12-verified CHUNKX), double-buffered. Block-local BN.
// ---------------------------------------------------------------------------
#define CHUNKX(ucv, LAST)                                                     \
    {                                                                         \
        if (!(LAST)) {                                                        \
            _Pragma("unroll")                                                 \
            for (int k = 0; k < 4; ++k) {                                     \
                int i4 = tid + k * 512;                                       \
                if (i4 < 1920) wr[k] = *(const float4*)(wnext + i4 * 4);      \
            }                                                                 \
            wnext += 7680;                                                    \
        }                                                                     \
        f32x4 acc[5];                                                         \
        _Pragma("unroll")                                                     \
        for (int nt = 0; nt < 5; ++nt) acc[nt] = (f32x4){0.f, 0.f, 0.f, 0.f};\
        _Pragma("unroll")                                                     \
        for (int ks = 0; ks < 3; ++ks) {                                      \
            _Pragma("unroll")                                                 \
            for (int nt = 0; nt < 5; ++nt) {                                  \
                half8 bf = *(const half8*)&Fcur[((ks * 5 + nt) * 64 + l) * 8];\
                acc[nt] = __builtin_amdgcn_mfma_f32_16x16x32_f16(             \
                    af[ks], bf, acc[nt], 0, 0, 0);                            \
            }                                                                 \
        }                                                                     \
        _Pragma("unroll")                                                     \
        for (int nt = 0; nt < 5; ++nt) {                                      \
            _Pragma("unroll")                                                 \
            for (int r = 0; r < 4; ++r)                                       \
                Mw[(hi * 4 + r) * 84 + nt * 16 + row16] = acc[nt][r];         \
        }                                                                     \
        WAVEBAR();                                                            \
        _Pragma("unroll")                                                     \
        for (int ul = 0; ul < 4; ++ul) {                                      \
            float lvx = lw[bQ * 20 + (ucv) * 4 + ul];                         \
            _Pragma("unroll")                                                 \
            for (int j = 0; j < 5; ++j)                                       \
                lacc[j] += lvx * Mw[bQ * 84 + ul * 20 + mh * 5 + j];          \
        }                                                                     \
        WAVEBAR();                                                            \
        __syncthreads();                                                      \
        if (!(LAST)) {                                                        \
            _Pragma("unroll")                                                 \
            for (int k = 0; k < 4; ++k) {                                     \
                int i4 = tid + k * 512;                                       \
                if (i4 < 1920) {                                              \
                    float vals[4] = {wr[k].x, wr[k].y, wr[k].z, wr[k].w};     \
                    _Pragma("unroll")                                         \
                    for (int t = 0; t < 4; ++t)                               \
                        Fnxt[sAddr[k][t]] = (_Float16)vals[t];                \
                }                                                             \
            }                                                                 \
        }                                                                     \
        __syncthreads();                                                      \
        { _Float16* t_ = Fcur; Fcur = Fnxt; Fnxt = t_; }                      \
    }

__global__ __launch_bounds__(512, 2)
void fused1_kernel(const float* __restrict__ x, const float* __restrict__ cores1,
                   const float* __restrict__ labv,
                   float* __restrict__ z1, float* __restrict__ gs, float* __restrict__ gq)
{
    __shared__ __align__(16) float xS[8 * 768];           // 24576 B
    __shared__ __align__(16) _Float16 Fbuf[2][7680];      // 30720 B
    __shared__ __align__(16) float MchunkS[8 * 16 * 84];  // 43008 B
    __shared__ __align__(16) float leftS[8 * 320];        // 10240 B
    __shared__ float redS[16];

    const int tid = threadIdx.x;                          // 0..511
    const int bid = blockIdx.x;
    const int p   = (bid & 7) * 32 + (bid >> 3);          // XCD swizzle (bijective on 256)
    const int wv  = tid >> 6, l = tid & 63;               // 8 waves
    float* xSw = xS + wv * 768;
    float* Mw  = MchunkS + wv * 1344;
    float* lw  = leftS + wv * 320;
    const int row16 = l & 15, hi = l >> 4;
    const int bQ = l >> 2,   mh = l & 3;
    const int hh  = (p >> 7) * 16 + ((p >> 2) & 15);
    const int ww0 = ((p >> 6) & 1) * 16 + (p & 3) * 4;

    // x preload: wave-private 16 rows x 48 c, one float4 per (b,c) = 4 sites
    float4 xr[12];
    #pragma unroll
    for (int k = 0; k < 12; ++k) {
        int idx = l + k * 64;                  // 0..767
        int br = idx / 48, c = idx - br * 48;
        xr[k] = *(const float4*)(x + (((size_t)((wv * 16 + br) * 48 + c)) << 10)
                                   + hh * 32 + ww0);
    }

    // chunk-invariant scatter addresses (R8-verified bijection), 4/thread
    int sAddr[4][4];
    #pragma unroll
    for (int k = 0; k < 4; ++k) {
        int i4 = tid + k * 512;
        if (i4 < 1920) {
            #pragma unroll
            for (int t = 0; t < 4; ++t) {
                int e = i4 * 4 + t;
                int v = e % 20;
                int r = e / 20;
                int f = r % 96;
                int ul = r / 96;
                int c = ul * 20 + v;
                sAddr[k][t] = (((f >> 5) * 5 + (c >> 4)) * 64 +
                               ((f >> 3) & 3) * 16 + (c & 15)) * 8 + (f & 7);
            }
        }
    }

    #pragma unroll
    for (int j = 0; j < 5; ++j) lw[bQ * 20 + mh * 5 + j] = VB;
    WAVEBAR();

    float lacc[5] = {0.f, 0.f, 0.f, 0.f, 0.f};
    float4 wr[4];
    const float* wnext = cores1 + (size_t)p * 153600;

    // prologue: load + scatter chunk 0 into Fbuf[0]
    #pragma unroll
    for (int k = 0; k < 4; ++k) {
        int i4 = tid + k * 512;
        if (i4 < 1920) wr[k] = *(const float4*)(wnext + i4 * 4);
    }
    wnext += 7680;
    _Float16* Fcur = &Fbuf[0][0];
    _Float16* Fnxt = &Fbuf[1][0];
    #pragma unroll
    for (int k = 0; k < 4; ++k) {
        int i4 = tid + k * 512;
        if (i4 < 1920) {
            float vals[4] = {wr[k].x, wr[k].y, wr[k].z, wr[k].w};
            #pragma unroll
            for (int t = 0; t < 4; ++t)
                Fcur[sAddr[k][t]] = (_Float16)vals[t];
        }
    }
    __syncthreads();

    #pragma unroll 1
    for (int n = 0; n < 4; ++n) {
        // site's x values from registers -> wave-private xS
        #pragma unroll
        for (int k = 0; k < 12; ++k) {
            int idx = l + k * 64;
            float v = (n == 0) ? xr[k].x : (n == 1) ? xr[k].y
                    : (n == 2) ? xr[k].z : xr[k].w;
            xSw[idx] = v;
        }
        WAVEBAR();
        half8 af[3];
        #pragma unroll
        for (int ks = 0; ks < 3; ++ks) {
            int f0 = ks * 32 + hi * 8;
            int cc = (f0 < 48) ? f0 : f0 - 48;
            float4 a  = *(const float4*)&xSw[row16 * 48 + cc];
            float4 b2 = *(const float4*)&xSw[row16 * 48 + cc + 4];
            float vv[8] = {a.x, a.y, a.z, a.w, b2.x, b2.y, b2.z, b2.w};
            bool inv = (f0 >= 48);
            half8 hv;
            #pragma unroll
            for (int j = 0; j < 8; ++j) hv[j] = (_Float16)(inv ? (1.f - vv[j]) : vv[j]);
            af[ks] = hv;
        }
        WAVEBAR();

        const bool last = (n == 3);
        CHUNKX(0, 0)
        CHUNKX(1, 0)
        CHUNKX(2, 0)
        CHUNKX(3, 0)
        CHUNKX(4, last)

        #pragma unroll
        for (int j = 0; j < 5; ++j) { lw[bQ * 20 + mh * 5 + j] = lacc[j]; lacc[j] = 0.f; }
        WAVEBAR();
    }

    // epilogue: labv matvec + z1 + block-local BN sums (no atomics)
    const float* lvp = labv + p * 400;
    #pragma unroll
    for (int k = 0; k < 7; ++k) { int i = l + k * 64; if (i < 400) Mw[i] = lvp[i]; }
    WAVEBAR();
    float yv[5] = {0.f, 0.f, 0.f, 0.f, 0.f};
    #pragma unroll
    for (int u = 0; u < 20; ++u) {
        float lu = lw[bQ * 20 + u];
        #pragma unroll
        for (int j = 0; j < 5; ++j) yv[j] += lu * Mw[u * 20 + mh * 5 + j];
    }
    float s = 0.f, s2 = 0.f;
    #pragma unroll
    for (int j = 0; j < 5; ++j) {
        z1[(size_t)(wv * 16 + bQ) * 5120 + p * 20 + mh * 5 + j] = yv[j];
        s += yv[j]; s2 += yv[j] * yv[j];
    }
    #pragma unroll
    for (int off = 32; off > 0; off >>= 1) {
        s  += __shfl_down(s, off);
        s2 += __shfl_down(s2, off);
    }
    if (l == 0) { redS[wv] = s; redS[8 + wv] = s2; }
    __syncthreads();
    if (tid == 0) {
        float S = 0.f, Q = 0.f;
        #pragma unroll
        for (int w2 = 0; w2 < 8; ++w2) { S += redS[w2]; Q += redS[8 + w2]; }
        gs[p] = S; gq[p] = Q;
    }
}

// ---------------------------------------------------------------------------
// Fused stages 2 & 3 (byte-identical to verified R12)
// ---------------------------------------------------------------------------
#define UCBODYN(ucv, CUR, NXT)                                                   \
    {                                                                            \
        if ((ucv) < 4) {                                                         \
            const _Float16* bptr = whp + (size_t)((ucv) + 1) * 5120;             \
            _Pragma("unroll")                                                    \
            for (int q = 0; q < 10; ++q)                                         \
                NXT[q] = *(const half8*)(bptr + (q * 64 + l) * 8);               \
        }                                                                        \
        f32x4 acc[5];                                                            \
        _Pragma("unroll")                                                        \
        for (int nt = 0; nt < 5; ++nt) acc[nt] = (f32x4){0.f, 0.f, 0.f, 0.f};    \
        _Pragma("unroll")                                                        \
        for (int ks = 0; ks < 2; ++ks) {                                         \
            _Pragma("unroll")                                                    \
            for (int nt = 0; nt < 5; ++nt)                                       \
                acc[nt] = __builtin_amdgcn_mfma_f32_16x16x32_f16(                \
                    af[ks], CUR[ks * 5 + nt], acc[nt], 0, 0, 0);                 \
        }                                                                        \
        _Pragma("unroll")                                                        \
        for (int nt = 0; nt < 5; ++nt) {                                         \
            _Pragma("unroll")                                                    \
            for (int r = 0; r < 4; ++r)                                          \
                Mw[(hi * 4 + r) * 84 + nt * 16 + row16] = acc[nt][r];            \
        }                                                                        \
        WAVEBAR();                                                               \
        _Pragma("unroll")                                                        \
        for (int ul = 0; ul < 4; ++ul) {                                         \
            float lvx = lw[bQ * 20 + (ucv) * 4 + ul];                            \
            _Pragma("unroll")                                                    \
            for (int j = 0; j < 5; ++j)                                          \
                lacc[j] += lvx * Mw[bQ * 84 + ul * 20 + mh * 5 + j];             \
        }                                                                        \
        WAVEBAR();                                                               \
    }

template <int STAGE>
__global__ __launch_bounds__(256, 2)
void fusedN_kernel(const float* __restrict__ zin, const _Float16* __restrict__ Wh,
                   const float* __restrict__ labv,
                   const float* __restrict__ gsin, const float* __restrict__ gqin,
                   const float* __restrict__ gam,  const float* __restrict__ bet,
                   float* __restrict__ zout,
                   float* __restrict__ gsout, float* __restrict__ gqout)
{
    constexpr int ZIN  = (STAGE == 2) ? 5120 : 1280;
    constexpr int ZOUT = (STAGE == 2) ? 1280 : 320;
    constexpr int JUMP = (STAGE == 2) ? 256 : 64;

    __shared__ __align__(16) float zS[4 * 320];
    __shared__ float scS[4 * 20], shS[4 * 20];
    __shared__ __align__(16) float MchunkS[4 * 16 * 84];
    __shared__ __align__(16) float leftS[4 * 320];

    const int tid = threadIdx.x;
    const int p   = blockIdx.x;
    const int bh  = blockIdx.y;
    const int wv  = tid >> 6, l = tid & 63;
    float* zSw = zS + wv * 320;
    float* scw = scS + wv * 20;
    float* shw = shS + wv * 20;
    float* Mw  = MchunkS + wv * 1344;
    float* lw  = leftS + wv * 320;
    const int row16 = l & 15, hi = l >> 4;
    const int bQ = l >> 2,   mh = l & 3;
    const int bg = bh * 64;

    #pragma unroll
    for (int j = 0; j < 5; ++j) lw[bQ * 20 + mh * 5 + j] = VB;
    WAVEBAR();

    float lacc[5] = {0.f, 0.f, 0.f, 0.f, 0.f};

    #pragma unroll 1
    for (int n = 0; n < 4; ++n) {
        int hh, ww;
        if (STAGE == 2) { hh = (p >> 5) * 8 + ((p >> 1) & 7); ww = ((p >> 4) & 1) * 8 + (p & 1) * 4 + n; }
        else            { hh = (p >> 3) * 4 + (p & 3);        ww = ((p >> 2) & 1) * 4 + n; }
        const int oo = (STAGE == 2) ? (hh * 16 + ww) : (hh * 8 + ww);

        if (l < 20) {
            int ch = (l * JUMP + oo) / 20;
            float mean = gsin[ch] * (1.f / 2560.f);
            float var  = gqin[ch] * (1.f / 2560.f) - mean * mean;
            float rstd = rsqrtf(var + 1e-5f);
            float sc = gam[ch] * rstd;
            scw[l] = sc;
            shw[l] = bet[ch] - mean * sc;
        }
        WAVEBAR();
        #pragma unroll
        for (int q = 0; q < 5; ++q) {
            int d = hi * 5 + q;
            float zraw = zin[(size_t)(bg + wv * 16 + row16) * ZIN + d * JUMP + oo];
            zSw[row16 * 20 + d] = zraw * scw[d] + shw[d];
        }
        WAVEBAR();
        half8 af[2];
        #pragma unroll
        for (int ks = 0; ks < 2; ++ks) {
            int f0 = ks * 32 + hi * 8;
            half8 hv;
            #pragma unroll
            for (int j = 0; j < 8; ++j) {
                int f = f0 + j;
                float val;
                if (f < 20)      val = zSw[row16 * 20 + f];
                else if (f < 40) val = 1.f - zSw[row16 * 20 + f - 20];
                else             val = 0.f;
                hv[j] = (_Float16)val;
            }
            af[ks] = hv;
        }
        WAVEBAR();

        const _Float16* whp = Wh + (size_t)((p * 4 + n) * 5) * 5120;
        half8 bA[10], bB[10];
        {
            #pragma unroll
            for (int q = 0; q < 10; ++q) bA[q] = *(const half8*)(whp + (q * 64 + l) * 8);
        }
        UCBODYN(0, bA, bB)
        UCBODYN(1, bB, bA)
        UCBODYN(2, bA, bB)
        UCBODYN(3, bB, bA)
        UCBODYN(4, bA, bB)

        #pragma unroll
        for (int j = 0; j < 5; ++j) { lw[bQ * 20 + mh * 5 + j] = lacc[j]; lacc[j] = 0.f; }
        WAVEBAR();
    }

    const float* lvp = labv + p * 400;
    #pragma unroll
    for (int k = 0; k < 7; ++k) { int i = l + k * 64; if (i < 400) Mw[i] = lvp[i]; }
    WAVEBAR();
    float yv[5] = {0.f, 0.f, 0.f, 0.f, 0.f};
    #pragma unroll
    for (int u = 0; u < 20; ++u) {
        float lu = lw[bQ * 20 + u];
        #pragma unroll
        for (int j = 0; j < 5; ++j) yv[j] += lu * Mw[u * 20 + mh * 5 + j];
    }
    float s = 0.f, s2 = 0.f;
    #pragma unroll
    for (int j = 0; j < 5; ++j) {
        zout[(size_t)(bg + wv * 16 + bQ) * ZOUT + p * 20 + mh * 5 + j] = yv[j];
        s += yv[j]; s2 += yv[j] * yv[j];
    }
    #pragma unroll
    for (int off = 32; off > 0; off >>= 1) {
        s  += __shfl_down(s, off);
        s2 += __shfl_down(s2, off);
    }
    if (l == 0) { atomicAdd(&gsout[p], s); atomicAdd(&gqout[p], s2); }
}

// ---------------------------------------------------------------------------
// Final MPS (byte-identical to verified R8-R12)
// ---------------------------------------------------------------------------
__global__ __launch_bounds__(256, 4)
void final_kernel(const float* __restrict__ z3,
                  const float* __restrict__ coresF,
                  const float* __restrict__ labelF,
                  const float* __restrict__ g3,
                  const float* __restrict__ b3,
                  const float* __restrict__ gsum3,
                  const float* __restrict__ gsq3,
                  float* __restrict__ out)
{
    __shared__ __align__(16) float fS[16 * 40];
    __shared__ __align__(16) float MS[16 * 400];
    __shared__ float lvS[200];
    __shared__ float scS[16], shS[16];
    __shared__ float leftS[20];

    const int b   = blockIdx.x;
    const int tid = threadIdx.x;

    if (tid < 16) {
        float mean = gsum3[tid] * (1.f / 2560.f);
        float var  = gsq3[tid] * (1.f / 2560.f) - mean * mean;
        float rstd = rsqrtf(var + 1e-5f);
        float sc   = g3[tid] * rstd;
        scS[tid] = sc;
        shS[tid] = b3[tid] - mean * sc;
    }
    __syncthreads();

    for (int i = tid; i < 640; i += 256) {
        int n = i / 40, f = i - n * 40;
        float raw = z3[(size_t)b * 320 + n * 20 + (f % 20)];
        float val = raw * scS[n] + shS[n];
        fS[i] = (f < 20) ? val : (1.f - val);
    }
    for (int i = tid; i < 200; i += 256) {
        int u = i / 10, o = i - u * 10;
        const float* lb = labelF + (size_t)(u * 10 + o) * 20;
        float s = 0.f;
        #pragma unroll
        for (int vv = 0; vv < 20; ++vv) s += lb[vv];
        lvS[i] = s * VB;
    }
    __syncthreads();

    for (int i = tid; i < 6400; i += 256) {
        int n = i / 400, uv = i - n * 400;
        int u = uv / 20, v = uv - u * 20;
        const float* wb = coresF + ((size_t)(n * 20 + u) * 40) * 20 + v;
        const float* fb = fS + n * 40;
        float acc = 0.f;
        #pragma unroll
        for (int f = 0; f < 40; ++f) acc += fb[f] * wb[f * 20];
        MS[i] = acc;
    }
    __syncthreads();

    if (tid < 64) {
        if (tid < 20) leftS[tid] = VB;
        WAVEBAR();
        #pragma unroll 1
        for (int n = 0; n < 16; ++n) {
            float tmp = 0.f;
            if (tid < 20) {
                #pragma unroll
                for (int u = 0; u < 20; ++u) tmp += leftS[u] * MS[n * 400 + u * 20 + tid];
            }
            WAVEBAR();
            if (tid < 20) leftS[tid] = tmp;
            WAVEBAR();
        }
        if (tid < 10) {
            float s = 0.f;
            #pragma unroll
            for (int u = 0; u < 20; ++u) s += leftS[u] * lvS[u * 10 + tid];
            out[b * 10 + tid] = s;
        }
    }
}

// ---------------------------------------------------------------------------
extern "C" void kernel_launch(void* const* d_in, const int* in_sizes, int n_in,
                              void* d_out, int out_size, void* d_ws, size_t ws_size,
                              hipStream_t stream)
{
    const float* x      = (const float*)d_in[0];
    const float* cores1 = (const float*)d_in[1];
    const float* label1 = (const float*)d_in[2];
    const float* g1     = (const float*)d_in[3];
    const float* b1     = (const float*)d_in[4];
    const float* cores2 = (const float*)d_in[5];
    const float* label2 = (const float*)d_in[6];
    const float* g2     = (const float*)d_in[7];
    const float* b2     = (const float*)d_in[8];
    const float* cores3 = (const float*)d_in[9];
    const float* label3 = (const float*)d_in[10];
    const float* g3     = (const float*)d_in[11];
    const float* b3     = (const float*)d_in[12];
    const float* coresF = (const float*)d_in[13];
    const float* labelF = (const float*)d_in[14];

    float* ws  = (float*)d_ws;
    float* z1  = ws + Z1_OFF;
    float* z2  = ws + Z2_OFF;
    float* z3  = ws + Z3_OFF;
    float* gs1 = ws + GS1_OFF; float* gq1 = ws + GQ1_OFF;
    float* gs2 = ws + GS2_OFF; float* gq2 = ws + GQ2_OFF;
    float* gs3 = ws + GS3_OFF; float* gq3 = ws + GQ3_OFF;
    float* lv1 = ws + LV1_OFF;
    float* lv2 = ws + LV2_OFF;
    float* lv3 = ws + LV3_OFF;
    _Float16* Wh2 = (_Float16*)(ws + WH2_OFF);
    _Float16* Wh3 = (_Float16*)(ws + WH3_OFF);

    prep_kernel<<<4337, 256, 0, stream>>>(cores2, cores3,
                                          label1, label2, label3,
                                          Wh2, Wh3,
                                          lv1, lv2, lv3, gs1);

    fused1_kernel<<<256, 512, 0, stream>>>(x, cores1, lv1, z1, gs1, gq1);
    fusedN_kernel<2><<<dim3(64, 2), 256, 0, stream>>>(z1, Wh2, lv2, gs1, gq1, g1, b1,
                                                      z2, gs2, gq2);
    fusedN_kernel<3><<<dim3(16, 2), 256, 0, stream>>>(z2, Wh3, lv3, gs2, gq2, g2, b2,
                                                      z3, gs3, gq3);
    final_kernel<<<128, 256, 0, stream>>>(z3, coresF, labelF, g3, b3,
                                          gs3, gq3, (float*)d_out);
}